// Round 7
// baseline (910.174 us; speedup 1.0000x reference)
//
#include <hip/hip_runtime.h>
#include <math.h>

#define DEVI __device__ __forceinline__

typedef unsigned short u16;
typedef __attribute__((ext_vector_type(4))) float f32x4;
typedef __attribute__((ext_vector_type(8))) short s16x8;
typedef __attribute__((ext_vector_type(4))) short s16x4;

constexpr int Bc = 4, Sc = 2048, Hc = 1024;
constexpr int NEc = 4, NCc = 16, CDc = 64, ODc = 128;
constexpr float TAUc = 0.5f, TEMPc = 0.07f, EPSc = 1e-5f;

DEVI float gelu_f(float x) { return 0.5f * x * (1.0f + erff(x * 0.7071067811865476f)); }

DEVI float bf2f(u16 u) { union { unsigned int i; float f; } v; v.i = ((unsigned int)u) << 16; return v.f; }
DEVI u16 f2bf(float f) {
  union { float f; unsigned int i; } v; v.f = f;
  unsigned int u = v.i;
  unsigned int r = (u + 0x7fffu + ((u >> 16) & 1u)) >> 16;
  return (u16)r;
}

DEVI float wred_sum(float v) {
  #pragma unroll
  for (int o = 32; o > 0; o >>= 1) v += __shfl_down(v, o);
  return v;
}
DEVI float wred_max(float v) {
  #pragma unroll
  for (int o = 32; o > 0; o >>= 1) v = fmaxf(v, __shfl_down(v, o));
  return v;
}

DEVI void gload16(const void* g, void* l) {
  __builtin_amdgcn_global_load_lds((const __attribute__((address_space(1))) void*)g,
                                   (__attribute__((address_space(3))) void*)l, 16, 0, 0);
}

// ---------------------------------------------------------------------------
// 256x256x64 8-wave deep-pipelined bf16 GEMM (T2 swizzle + T3/T4 counted vmcnt
// + T5 setprio). C = act(scale*(A @ Bt^T) + bias) (+resid).
// A: [M][K] bf16. Bt: [N][K] bf16. M%256==0, N%256==0, K%64==0, grid%8==0.
// EPI bits: 1=bias, 2=gelu, 4=resid.
// amdgpu_waves_per_eu(2,2): pin the backend's occupancy target to 2 waves/EU
// (= 1 block/CU, which the 128 KiB LDS forces anyway) so the register
// allocator gets the full 256-VGPR budget. Without it the scheduler's default
// heuristic targeted 4 waves/EU (VGPR_Count=128) and spilled the whole
// acc[8][4] -> ~950 MB scratch traffic/dispatch (rounds 5-6, 426 us vs
// expected ~60 us). launch_bounds(512,N) did NOT control this (N is min
// waves/EU, not a VGPR cap at these values).
// ---------------------------------------------------------------------------
template<int EPI>
__global__ __launch_bounds__(512)
__attribute__((amdgpu_waves_per_eu(2, 2)))
void gemm8(
    const u16* __restrict__ A, long sAz, int lda,
    const u16* __restrict__ Bt, long sBz, int ldb,
    u16* __restrict__ C, long sCz, int ldc,
    const float* __restrict__ bias,
    const u16* __restrict__ resid, long sRz,
    float scale, int N, int K)
{
  const int bz = blockIdx.z;
  A += (long)bz * sAz; Bt += (long)bz * sBz; C += (long)bz * sCz;
  const u16* Rp = (EPI & 4) ? (resid + (long)bz * sRz) : nullptr;

  int bid = blockIdx.x;
  const int nwg = gridDim.x;
  bid = ((bid & 7) * (nwg >> 3)) + (bid >> 3);   // XCD swizzle (grid %8==0)
  const int nTn = N >> 8;
  const int tm = bid / nTn, tn = bid - tm * nTn;

  const int tid = threadIdx.x;
  const int lane = tid & 63;
  const int wid = tid >> 6;
  const int wm = wid >> 2, wn = wid & 3;
  const int l15 = lane & 15, l4 = lane >> 4;

  __shared__ u16 pool[65536];   // 128 KiB: A dbuf 2x16K elems, B dbuf 2x16K

  const int nkt = K >> 6;
  const int srow = tid >> 3, schunk = tid & 7;

  const u16* Ab = A + (long)(tm * 256) * lda;
  const u16* Bb = Bt + (long)(tn * 256) * ldb;

  // stage one 128-row half-tile (2 x gload16/thread). LDS linear; global
  // source pre-swizzled by the same XOR the reads use (involution).
  auto stA = [&](int b, int h, int kt) {
    #pragma unroll
    for (int L = 0; L < 2; ++L) {
      const int lr = h * 128 + srow + L * 64;
      gload16(Ab + (long)lr * lda + (kt << 6) + ((schunk ^ (lr & 7)) << 3),
              &pool[b * 16384 + lr * 64 + schunk * 8]);
    }
  };
  auto stB = [&](int b, int h, int kt) {
    #pragma unroll
    for (int L = 0; L < 2; ++L) {
      const int lr = h * 128 + srow + L * 64;
      gload16(Bb + (long)lr * ldb + (kt << 6) + ((schunk ^ (lr & 7)) << 3),
              &pool[32768 + b * 16384 + lr * 64 + schunk * 8]);
    }
  };

  f32x4 acc[8][4];
  #pragma unroll
  for (int m = 0; m < 8; ++m)
    #pragma unroll
    for (int n = 0; n < 4; ++n) acc[m][n] = f32x4{0.f, 0.f, 0.f, 0.f};

  // ds-read addressing: row&7 == l15&7 (row bases are %8==0) -> XOR is lane-const
  const int aBase = (wm * 128 + l15) * 64;
  const int bBase = 32768 + (wn * 64 + l15) * 64;
  const int cx0 = ((l4 ^ (l15 & 7)) << 3);
  const int cx1 = (((4 + l4) ^ (l15 & 7)) << 3);

  s16x8 af[4], bf[2][4];

  // prologue: kt0 fully, kt1's B + A-h0 (7 half-tiles); 3 newest stay in flight
  stA(0, 0, 0); stA(0, 1, 0); stB(0, 0, 0); stB(0, 1, 0);
  if (nkt > 1) {
    stB(1, 0, 1); stB(1, 1, 1); stA(1, 0, 1);
    asm volatile("s_waitcnt vmcnt(6)" ::: "memory");
  } else {
    asm volatile("s_waitcnt vmcnt(0)" ::: "memory");
  }
  __builtin_amdgcn_s_barrier();

  for (int kt = 0; kt < nkt; ++kt) {
    const int b = kt & 1, bb16 = b * 16384;
    // ---------------- phase 0 ----------------
    #pragma unroll
    for (int m = 0; m < 4; ++m) af[m] = *(const s16x8*)&pool[bb16 + aBase + m * 1024 + cx0];
    #pragma unroll
    for (int n = 0; n < 4; ++n) bf[0][n] = *(const s16x8*)&pool[bb16 + bBase + n * 1024 + cx0];
    __builtin_amdgcn_sched_barrier(0);
    __builtin_amdgcn_s_barrier();
    asm volatile("s_waitcnt lgkmcnt(0)" ::: "memory");
    __builtin_amdgcn_sched_barrier(0);
    if (kt + 1 < nkt) stA(b ^ 1, 1, kt + 1);
    __builtin_amdgcn_s_setprio(1);
    #pragma unroll
    for (int m = 0; m < 4; ++m)
      #pragma unroll
      for (int n = 0; n < 4; ++n)
        acc[m][n] = __builtin_amdgcn_mfma_f32_16x16x32_bf16(af[m], bf[0][n], acc[m][n], 0, 0, 0);
    __builtin_amdgcn_s_setprio(0);
    __builtin_amdgcn_sched_barrier(0);
    __builtin_amdgcn_s_barrier();
    // ---------------- phase 1 ----------------
    #pragma unroll
    for (int m = 0; m < 4; ++m) af[m] = *(const s16x8*)&pool[bb16 + aBase + m * 1024 + cx1];
    #pragma unroll
    for (int n = 0; n < 4; ++n) bf[1][n] = *(const s16x8*)&pool[bb16 + bBase + n * 1024 + cx1];
    __builtin_amdgcn_sched_barrier(0);
    __builtin_amdgcn_s_barrier();
    asm volatile("s_waitcnt lgkmcnt(0)" ::: "memory");
    __builtin_amdgcn_sched_barrier(0);
    if (kt + 2 < nkt) stB(b, 0, kt + 2);
    __builtin_amdgcn_s_setprio(1);
    #pragma unroll
    for (int m = 0; m < 4; ++m)
      #pragma unroll
      for (int n = 0; n < 4; ++n)
        acc[m][n] = __builtin_amdgcn_mfma_f32_16x16x32_bf16(af[m], bf[1][n], acc[m][n], 0, 0, 0);
    __builtin_amdgcn_s_setprio(0);
    __builtin_amdgcn_sched_barrier(0);
    __builtin_amdgcn_s_barrier();
    // ---------------- phase 2 ----------------
    #pragma unroll
    for (int m = 0; m < 4; ++m) af[m] = *(const s16x8*)&pool[bb16 + aBase + (m + 4) * 1024 + cx0];
    __builtin_amdgcn_sched_barrier(0);
    __builtin_amdgcn_s_barrier();
    asm volatile("s_waitcnt lgkmcnt(0)" ::: "memory");
    __builtin_amdgcn_sched_barrier(0);
    if (kt + 2 < nkt) stB(b, 1, kt + 2);
    __builtin_amdgcn_s_setprio(1);
    #pragma unroll
    for (int m = 0; m < 4; ++m)
      #pragma unroll
      for (int n = 0; n < 4; ++n)
        acc[m + 4][n] = __builtin_amdgcn_mfma_f32_16x16x32_bf16(af[m], bf[0][n], acc[m + 4][n], 0, 0, 0);
    __builtin_amdgcn_s_setprio(0);
    __builtin_amdgcn_sched_barrier(0);
    __builtin_amdgcn_s_barrier();
    // ---------------- phase 3 ----------------
    #pragma unroll
    for (int m = 0; m < 4; ++m) af[m] = *(const s16x8*)&pool[bb16 + aBase + (m + 4) * 1024 + cx1];
    __builtin_amdgcn_sched_barrier(0);
    __builtin_amdgcn_s_barrier();
    asm volatile("s_waitcnt lgkmcnt(0)" ::: "memory");
    __builtin_amdgcn_sched_barrier(0);
    if (kt + 2 < nkt) stA(b, 0, kt + 2);
    __builtin_amdgcn_s_setprio(1);
    #pragma unroll
    for (int m = 0; m < 4; ++m)
      #pragma unroll
      for (int n = 0; n < 4; ++n)
        acc[m + 4][n] = __builtin_amdgcn_mfma_f32_16x16x32_bf16(af[m], bf[1][n], acc[m + 4][n], 0, 0, 0);
    __builtin_amdgcn_s_setprio(0);
    if (kt < nkt - 2) asm volatile("s_waitcnt vmcnt(6)" ::: "memory");
    else              asm volatile("s_waitcnt vmcnt(0)" ::: "memory");
    __builtin_amdgcn_sched_barrier(0);
    __builtin_amdgcn_s_barrier();
  }

  // ---- epilogue: 2 passes of 128 rows via LDS [128][264], coalesced stores
  float bvn[4];
  #pragma unroll
  for (int n = 0; n < 4; ++n)
    bvn[n] = (EPI & 1) ? bias[tn * 256 + wn * 64 + n * 16 + l15] : 0.f;

  for (int p = 0; p < 2; ++p) {
    if (wm == p) {
      #pragma unroll
      for (int m = 0; m < 8; ++m)
        #pragma unroll
        for (int n = 0; n < 4; ++n) {
          const int lc = wn * 64 + n * 16 + l15;
          #pragma unroll
          for (int r = 0; r < 4; ++r) {
            float v = acc[m][n][r] * scale + bvn[n];
            if (EPI & 2) v = gelu_f(v);
            pool[(m * 16 + l4 * 4 + r) * 264 + lc] = f2bf(v);
          }
        }
    }
    __syncthreads();
    const long gr0 = (long)tm * 256 + p * 128;
    #pragma unroll
    for (int it = 0; it < 8; ++it) {
      const int row = (tid >> 5) + it * 16;
      const int ch = tid & 31;
      const long Gr = gr0 + row;
      const int col0 = tn * 256 + ch * 8;
      s16x8 cv = *(s16x8*)&pool[row * 264 + ch * 8];
      if (EPI & 4) {
        const s16x8 rv = *(const s16x8*)&Rp[Gr * ldc + col0];
        #pragma unroll
        for (int e = 0; e < 8; ++e)
          cv[e] = (short)f2bf(bf2f((u16)cv[e]) + bf2f((u16)rv[e]));
      }
      *(s16x8*)&C[Gr * ldc + col0] = cv;
    }
    __syncthreads();
  }
}

// ---------------------------------------------------------------------------
// m97-style 128x128x32 GEMM, kept for the transposed-store V projection only.
// EPI bits: 1=bias, 8=transposed store.
// ---------------------------------------------------------------------------
template<int EPI>
__global__ __launch_bounds__(256, 3) void gemm_bt(
    const u16* __restrict__ A, long sAz, int lda,
    const u16* __restrict__ Bt, long sBz, int ldb,
    u16* __restrict__ C, long sCz, int ldc,
    const float* __restrict__ bias,
    const u16* __restrict__ resid, long sRz,
    float scale, int M, int N, int K)
{
  const int bz = blockIdx.z;
  A += (long)bz * sAz; Bt += (long)bz * sBz; C += (long)bz * sCz;
  if (EPI & 4) resid += (long)bz * sRz;

  int bid = blockIdx.x;
  const int nwg = gridDim.x;
  if ((nwg & 7) == 0) bid = ((bid & 7) * (nwg >> 3)) + (bid >> 3);

  const int nTn = N >> 7;
  const int tm = bid / nTn, tn = bid % nTn;
  const int tid = threadIdx.x;
  const int wid = tid >> 6, lane = tid & 63;
  const int wr = wid >> 1, wc = wid & 1;
  const int l15 = lane & 15, l4 = lane >> 4;

  __shared__ u16 smem[9216];
  u16* As = smem;
  u16* Bs = smem + 4096;

  f32x4 acc[4][4];
  #pragma unroll
  for (int i = 0; i < 4; ++i)
    #pragma unroll
    for (int j = 0; j < 4; ++j) acc[i][j] = f32x4{0.f, 0.f, 0.f, 0.f};

  const int srow = (wid << 5) + (lane >> 2);
  const int scol = (lane & 3) << 3;
  const u16* aS = A + (long)(tm * 128 + srow) * lda + scol;
  const u16* bS = Bt + (long)(tn * 128 + srow) * ldb + scol;
  const long aStep16 = (long)16 * lda;
  const long bStep16 = (long)16 * ldb;
  u16* aD = &As[wid * 32 * 32];
  u16* bD = &Bs[wid * 32 * 32];

  for (int k0 = 0; k0 < K; k0 += 32) {
    gload16(aS, aD);
    gload16(aS + aStep16, aD + 16 * 32);
    gload16(bS, bD);
    gload16(bS + bStep16, bD + 16 * 32);
    __syncthreads();
    s16x8 af[4], bfr[4];
    #pragma unroll
    for (int i = 0; i < 4; ++i) {
      const int row = (wr << 6) + (i << 4) + l15;
      af[i] = *(const s16x8*)&As[(row << 5) + (l4 << 3)];
    }
    #pragma unroll
    for (int j = 0; j < 4; ++j) {
      const int col = (wc << 6) + (j << 4) + l15;
      bfr[j] = *(const s16x8*)&Bs[(col << 5) + (l4 << 3)];
    }
    #pragma unroll
    for (int i = 0; i < 4; ++i)
      #pragma unroll
      for (int j = 0; j < 4; ++j)
        acc[i][j] = __builtin_amdgcn_mfma_f32_16x16x32_bf16(af[i], bfr[j], acc[i][j], 0, 0, 0);
    __syncthreads();
    aS += 32; bS += 32;
  }

  if (!(EPI & 8)) {
    u16 (*Cs)[128] = (u16(*)[128])smem;
    #pragma unroll
    for (int p = 0; p < 2; ++p) {
      if (wr == p) {
        #pragma unroll
        for (int j = 0; j < 4; ++j) {
          const int c = (wc << 6) + (j << 4) + l15;
          const float bv = (EPI & 1) ? bias[tn * 128 + c] : 0.f;
          #pragma unroll
          for (int i = 0; i < 4; ++i) {
            const int lr = (i << 4) + (l4 << 2);
            #pragma unroll
            for (int r = 0; r < 4; ++r) {
              float v = acc[i][j][r] * scale + bv;
              if (EPI & 2) v = gelu_f(v);
              Cs[lr + r][c] = f2bf(v);
            }
          }
        }
      }
      __syncthreads();
      #pragma unroll
      for (int it = 0; it < 4; ++it) {
        const int row = (tid >> 4) + (it << 4);
        const int chunk = tid & 15;
        const long Gr = tm * 128 + (p << 6) + row;
        const int col0 = tn * 128 + (chunk << 3);
        s16x8 cv = *(s16x8*)&Cs[row][chunk << 3];
        if (EPI & 4) {
          const s16x8 rv = *(const s16x8*)&resid[Gr * ldc + col0];
          #pragma unroll
          for (int e = 0; e < 8; ++e)
            cv[e] = (short)f2bf(bf2f((u16)cv[e]) + bf2f((u16)rv[e]));
        }
        *(s16x8*)&C[Gr * ldc + col0] = cv;
      }
      if (p == 0) __syncthreads();
    }
  } else {
    u16 (*Ct)[136] = (u16(*)[136])smem;
    #pragma unroll
    for (int p = 0; p < 2; ++p) {
      if (wc == p) {
        #pragma unroll
        for (int j = 0; j < 4; ++j) {
          const int lc = (j << 4) + l15;
          const float bv = (EPI & 1) ? bias[tn * 128 + (p << 6) + lc] : 0.f;
          #pragma unroll
          for (int i = 0; i < 4; ++i) {
            const int row_lo = (wr << 6) + (i << 4) + (l4 << 2);
            s16x4 pk;
            #pragma unroll
            for (int r = 0; r < 4; ++r) {
              float v = acc[i][j][r] * scale + bv;
              if (EPI & 2) v = gelu_f(v);
              pk[r] = (short)f2bf(v);
            }
            *(s16x4*)&Ct[lc][row_lo] = pk;
          }
        }
      }
      __syncthreads();
      #pragma unroll
      for (int it = 0; it < 4; ++it) {
        const int lc = (tid >> 4) + (it << 4);
        const int chunk = tid & 15;
        const long Gc = tn * 128 + (p << 6) + lc;
        const int col0 = tm * 128 + (chunk << 3);
        s16x8 cv = *(s16x8*)&Ct[lc][chunk << 3];
        *(s16x8*)&C[Gc * ldc + col0] = cv;
      }
      if (p == 0) __syncthreads();
    }
  }
}

// ---------------------------------------------------------------------------
__global__ void transpose_w_k(const float* __restrict__ in, u16* __restrict__ out, int K, int N) {
  __shared__ float t[32][33];
  const int n0 = blockIdx.x << 5, k0 = blockIdx.y << 5;
  const int tx = threadIdx.x, ty = threadIdx.y;
  #pragma unroll
  for (int i = 0; i < 32; i += 8)
    t[ty + i][tx] = in[(long)(k0 + ty + i) * N + n0 + tx];
  __syncthreads();
  #pragma unroll
  for (int i = 0; i < 32; i += 8)
    out[(long)(n0 + ty + i) * K + k0 + tx] = f2bf(t[tx][ty + i]);
}

__global__ void transpose_w4_k(const float* __restrict__ w0, const float* __restrict__ w1,
                               const float* __restrict__ w2, const float* __restrict__ w3,
                               u16* __restrict__ o0, u16* __restrict__ o1,
                               u16* __restrict__ o2, u16* __restrict__ o3) {
  const int z = blockIdx.z;
  const float* in = (z == 0) ? w0 : (z == 1) ? w1 : (z == 2) ? w2 : w3;
  u16* out = (z == 0) ? o0 : (z == 1) ? o1 : (z == 2) ? o2 : o3;
  __shared__ float t[32][33];
  const int n0 = blockIdx.x << 5, k0 = blockIdx.y << 5;
  const int tx = threadIdx.x, ty = threadIdx.y;
  #pragma unroll
  for (int i = 0; i < 32; i += 8)
    t[ty + i][tx] = in[(long)(k0 + ty + i) * Hc + n0 + tx];
  __syncthreads();
  #pragma unroll
  for (int i = 0; i < 32; i += 8)
    out[(long)(n0 + ty + i) * Hc + k0 + tx] = f2bf(t[tx][ty + i]);
}

__global__ void concat_bias_k(const float* __restrict__ a, const float* __restrict__ b,
                              float* __restrict__ o) {
  const int i = (blockIdx.x << 8) + threadIdx.x;
  o[i] = (i < Hc) ? a[i] : b[i - Hc];
}

// ---------------------------------------------------------------------------
__global__ void pool_partial_k(const float* __restrict__ hs, const int* __restrict__ mask,
                               float* __restrict__ part) {
  const int h = (blockIdx.x << 8) + threadIdx.x;
  const int c = blockIdx.y, b = blockIdx.z;
  const int s0 = c * (Sc / 16);
  float acc = 0.f;
  for (int i = 0; i < Sc / 16; ++i) {
    const int s = s0 + i;
    acc += hs[((long)b * Sc + s) * Hc + h] * (float)mask[b * Sc + s];
  }
  part[((b << 4) + c) * Hc + h] = acc;
}

__global__ void pool_final_k(const float* __restrict__ part, const int* __restrict__ mask,
                             float* __restrict__ pooled) {
  const int b = blockIdx.x;
  __shared__ float red[4];
  __shared__ float denom_s;
  float d = 0.f;
  for (int i = threadIdx.x; i < Sc; i += 256) d += (float)mask[b * Sc + i];
  d = wred_sum(d);
  if ((threadIdx.x & 63) == 0) red[threadIdx.x >> 6] = d;
  __syncthreads();
  if (threadIdx.x == 0) denom_s = red[0] + red[1] + red[2] + red[3] + 1e-8f;
  __syncthreads();
  const float inv = 1.f / denom_s;
  for (int h = threadIdx.x; h < Hc; h += 256) {
    float s = 0.f;
    #pragma unroll
    for (int c = 0; c < 16; ++c) s += part[((b << 4) + c) * Hc + h];
    pooled[b * Hc + h] = s * inv;
  }
}

// ---------------------------------------------------------------------------
template<int R>
__global__ void mrow_part_k(const float* __restrict__ in, const float* __restrict__ W,
                            float* __restrict__ part, int K, int N) {
  const int t = threadIdx.x;
  const int jj = t & 31;
  const int j = (blockIdx.x << 5) + jj;
  const int ks = t >> 5;
  const int nchunk = gridDim.y;
  const int Kc = K / (nchunk << 3);
  const int k0 = ((blockIdx.y << 3) + ks) * Kc;
  float acc[R];
  #pragma unroll
  for (int r = 0; r < R; ++r) acc[r] = 0.f;
  for (int k = k0; k < k0 + Kc; ++k) {
    const float wv = W[(long)k * N + j];
    #pragma unroll
    for (int r = 0; r < R; ++r) acc[r] = fmaf(in[r * K + k], wv, acc[r]);
  }
  __shared__ float sm[8][R][32];
  #pragma unroll
  for (int r = 0; r < R; ++r) sm[ks][r][jj] = acc[r];
  __syncthreads();
  for (int idx = t; idx < R * 32; idx += 256) {
    const int r = idx >> 5, j2 = idx & 31;
    float s = 0.f;
    #pragma unroll
    for (int q = 0; q < 8; ++q) s += sm[q][r][j2];
    part[(long)(blockIdx.y * R + r) * N + (blockIdx.x << 5) + j2] = s;
  }
}

template<bool GELU>
__global__ void mrow_reduce_k(const float* __restrict__ part, const float* __restrict__ bias,
                              float* __restrict__ out, int N, int R, int nchunk) {
  const int idx = (blockIdx.x << 8) + threadIdx.x;
  if (idx >= R * N) return;
  const int r = idx / N, j = idx - r * N;
  float s = 0.f;
  for (int c = 0; c < nchunk; ++c) s += part[(long)(c * R + r) * N + j];
  if (bias) s += bias[j];
  if (GELU) s = gelu_f(s);
  out[(long)r * N + j] = s;
}

__global__ void ln_rows_k(float* __restrict__ x, const float* __restrict__ g,
                          const float* __restrict__ b) {
  const long base = (long)blockIdx.x * Hc;
  __shared__ float red[4];
  float v[4]; float s = 0.f;
  #pragma unroll
  for (int i = 0; i < 4; ++i) { v[i] = x[base + threadIdx.x + (i << 8)]; s += v[i]; }
  s = wred_sum(s);
  if ((threadIdx.x & 63) == 0) red[threadIdx.x >> 6] = s;
  __syncthreads();
  const float mean = (red[0] + red[1] + red[2] + red[3]) * (1.f / Hc);
  float q = 0.f;
  #pragma unroll
  for (int i = 0; i < 4; ++i) { const float d2 = v[i] - mean; q += d2 * d2; }
  __syncthreads();
  q = wred_sum(q);
  if ((threadIdx.x & 63) == 0) red[threadIdx.x >> 6] = q;
  __syncthreads();
  const float var = (red[0] + red[1] + red[2] + red[3]) * (1.f / Hc);
  const float inv = rsqrtf(var + EPSc);
  #pragma unroll
  for (int i = 0; i < 4; ++i) {
    const int col = threadIdx.x + (i << 8);
    x[base + col] = (v[i] - mean) * inv * g[col] + b[col];
  }
}

__global__ void gumbel_k(const float* __restrict__ z, const float* __restrict__ gn,
                         const float* __restrict__ cb, float* __restrict__ zcodes) {
  const int b = blockIdx.x, t = threadIdx.x;
  if (t >= NEc) return;
  const float* zp = z + b * (NEc * NCc) + t * NCc;
  const float* gp = gn + (b * NEc + t) * NCc;
  int best = 0; float bv = -3.4e38f;
  for (int c2 = 0; c2 < NCc; ++c2) {
    const float val = (zp[c2] + gp[c2]) * (1.f / TAUc);
    if (val > bv) { bv = val; best = c2; }
  }
  for (int d2 = 0; d2 < CDc; ++d2)
    zcodes[(b * NEc + t) * CDc + d2] = cb[best * CDc + d2];
}

__global__ void build_hwk_k(const float* __restrict__ hctx, const float* __restrict__ zcodes,
                            float* __restrict__ hwk) {
  const int r = blockIdx.x;
  const int b = r >> 2;
  for (int i = threadIdx.x; i < Hc + CDc; i += 256)
    hwk[r * (Hc + CDc) + i] = (i < Hc) ? hctx[b * Hc + i] : zcodes[r * CDc + (i - Hc)];
}

__global__ void select_k(const float* __restrict__ tv, const float* __restrict__ outc,
                         float* __restrict__ chosen) {
  const int b = blockIdx.x, t = threadIdx.x;
  __shared__ float red[2];
  __shared__ float ig[NEc];
  __shared__ int bestIdx;
  const float x = tv[b * ODc + t];
  float ss = wred_sum(x * x);
  if ((t & 63) == 0) red[t >> 6] = ss;
  __syncthreads();
  float nrm = fmaxf(sqrtf(red[0] + red[1]), 1e-12f);
  const float tvn = x / nrm;
  __syncthreads();
  for (int ne = 0; ne < NEc; ++ne) {
    const float o = outc[(b * NEc + ne) * ODc + t];
    float a = wred_sum(o * o);
    float d2 = wred_sum(o * tvn);
    if ((t & 63) == 0) red[t >> 6] = a;
    __syncthreads();
    const float no = sqrtf(red[0] + red[1]);
    __syncthreads();
    if ((t & 63) == 0) red[t >> 6] = d2;
    __syncthreads();
    const float dd = red[0] + red[1];
    if (t == 0) ig[ne] = dd / fmaxf(no, 1e-12f) * (1.f / TEMPc);
    __syncthreads();
  }
  if (t == 0) {
    int bi = 0; float bvv = ig[0];
    for (int ne = 1; ne < NEc; ++ne) if (ig[ne] > bvv) { bvv = ig[ne]; bi = ne; }
    bestIdx = bi;
  }
  __syncthreads();
  chosen[b * ODc + t] = outc[(b * NEc + bestIdx) * ODc + t];
}

__global__ void fuse_k(const float* __restrict__ hs, const float* __restrict__ gb,
                       u16* __restrict__ fused) {
  const long i = (((long)blockIdx.x << 8) + threadIdx.x) << 2;
  const int h = (int)(i & (Hc - 1));
  const int b = (int)(i >> 21);
  const float4 xv = *(const float4*)(hs + i);
  const float* gp = gb + b * 2048;
  s16x4 pk = { (short)f2bf(fmaf(gp[h + 0], xv.x, gp[Hc + h + 0])),
               (short)f2bf(fmaf(gp[h + 1], xv.y, gp[Hc + h + 1])),
               (short)f2bf(fmaf(gp[h + 2], xv.z, gp[Hc + h + 2])),
               (short)f2bf(fmaf(gp[h + 3], xv.w, gp[Hc + h + 3])) };
  *(s16x4*)(fused + i) = pk;
}

__global__ void softmax_k(u16* __restrict__ sc, const int* __restrict__ mask) {
  const long base = (long)blockIdx.x * Sc;
  const int b = blockIdx.x / Sc;
  __shared__ float red[4];
  float x[8];
  float mx = -3.0e38f;
  #pragma unroll
  for (int i = 0; i < 8; ++i) {
    const int col = threadIdx.x + (i << 8);
    float v = bf2f(sc[base + col]);
    if (mask[b * Sc + col] == 0) v = -3.0e38f;
    x[i] = v;
    mx = fmaxf(mx, v);
  }
  mx = wred_max(mx);
  if ((threadIdx.x & 63) == 0) red[threadIdx.x >> 6] = mx;
  __syncthreads();
  mx = fmaxf(fmaxf(red[0], red[1]), fmaxf(red[2], red[3]));
  float sum = 0.f;
  #pragma unroll
  for (int i = 0; i < 8; ++i) { x[i] = __expf(x[i] - mx); sum += x[i]; }
  __syncthreads();
  sum = wred_sum(sum);
  if ((threadIdx.x & 63) == 0) red[threadIdx.x >> 6] = sum;
  __syncthreads();
  const float inv = 1.f / (red[0] + red[1] + red[2] + red[3]);
  #pragma unroll
  for (int i = 0; i < 8; ++i)
    sc[base + threadIdx.x + (i << 8)] = f2bf(x[i] * inv);
}

__global__ void final_ln_k(const u16* __restrict__ ff, const u16* __restrict__ fused,
                           const float* __restrict__ g, const float* __restrict__ b,
                           float* __restrict__ out) {
  const long base = (long)blockIdx.x * Hc;
  __shared__ float red[4];
  float v[4]; float s = 0.f;
  #pragma unroll
  for (int i = 0; i < 4; ++i) {
    const int col = threadIdx.x + (i << 8);
    v[i] = bf2f(ff[base + col]) + bf2f(fused[base + col]);
    s += v[i];
  }
  s = wred_sum(s);
  if ((threadIdx.x & 63) == 0) red[threadIdx.x >> 6] = s;
  __syncthreads();
  const float mean = (red[0] + red[1] + red[2] + red[3]) * (1.f / Hc);
  float q = 0.f;
  #pragma unroll
  for (int i = 0; i < 4; ++i) { const float d2 = v[i] - mean; q += d2 * d2; }
  __syncthreads();
  q = wred_sum(q);
  if ((threadIdx.x & 63) == 0) red[threadIdx.x >> 6] = q;
  __syncthreads();
  const float var = (red[0] + red[1] + red[2] + red[3]) * (1.f / Hc);
  const float inv = rsqrtf(var + EPSc);
  #pragma unroll
  for (int i = 0; i < 4; ++i) {
    const int col = threadIdx.x + (i << 8);
    out[base + col] = (v[i] - mean) * inv * g[col] + b[col];
  }
}

// ---------------------------------------------------------------------------
extern "C" void kernel_launch(void* const* d_in, const int* in_sizes, int n_in,
                              void* d_out, int out_size, void* d_ws, size_t ws_size,
                              hipStream_t stream) {
  const float* hs       = (const float*)d_in[0];
  const int*   amask    = (const int*)d_in[1];
  const float* gn       = (const float*)d_in[2];
  const float* cp_w     = (const float*)d_in[3];
  const float* cp_b     = (const float*)d_in[4];
  const float* cp_ln_g  = (const float*)d_in[5];
  const float* cp_ln_b  = (const float*)d_in[6];
  const float* eph_w1   = (const float*)d_in[7];
  const float* eph_b1   = (const float*)d_in[8];
  const float* eph_w2   = (const float*)d_in[9];
  const float* eph_b2   = (const float*)d_in[10];
  const float* codebook = (const float*)d_in[11];
  const float* wk_w1    = (const float*)d_in[12];
  const float* wk_b1    = (const float*)d_in[13];
  const float* wk_w2    = (const float*)d_in[14];
  const float* wk_b2    = (const float*)d_in[15];
  const float* tp_w     = (const float*)d_in[16];
  const float* film_w   = (const float*)d_in[17];
  const float* film_b   = (const float*)d_in[18];
  const float* q_w      = (const float*)d_in[19];
  const float* q_bias   = (const float*)d_in[20];
  const float* k_w      = (const float*)d_in[21];
  const float* k_bias   = (const float*)d_in[22];
  const float* v_w      = (const float*)d_in[23];
  const float* v_bias   = (const float*)d_in[24];
  const float* o_w      = (const float*)d_in[25];
  const float* o_bias   = (const float*)d_in[26];
  const float* int_w    = (const float*)d_in[27];
  const float* int_b    = (const float*)d_in[28];
  const float* out_w    = (const float*)d_in[29];
  const float* out_b    = (const float*)d_in[30];
  const float* ln_g     = (const float*)d_in[31];
  const float* ln_b     = (const float*)d_in[32];
  float* outp = (float*)d_out;

  char* w = (char*)d_ws;
  auto alloc = [&](size_t bytes) -> char* {
    char* p = w; w += (bytes + 255) & ~(size_t)255; return p;
  };
  float* part    = (float*)alloc((size_t)Bc * 16 * Hc * 4);
  float* pooled  = (float*)alloc((size_t)Bc * Hc * 4);
  float* hctx    = (float*)alloc((size_t)Bc * Hc * 4);
  float* t1      = (float*)alloc((size_t)Bc * Hc * 4);
  float* zlog    = (float*)alloc((size_t)Bc * 64 * 4);
  float* zcodes  = (float*)alloc((size_t)Bc * NEc * CDc * 4);
  float* hwk     = (float*)alloc((size_t)16 * (Hc + CDc) * 4);
  float* wkt1    = (float*)alloc((size_t)16 * 2048 * 4);
  float* outcome = (float*)alloc((size_t)16 * ODc * 4);
  float* tvb     = (float*)alloc((size_t)Bc * ODc * 4);
  float* chosen  = (float*)alloc((size_t)Bc * ODc * 4);
  float* gb      = (float*)alloc((size_t)Bc * 2048 * 4);
  float* lin_part= (float*)alloc((size_t)1024 * 1024);
  float* qk_bias = (float*)alloc((size_t)2048 * 4);
  u16* qT    = (u16*)alloc((size_t)Hc * Hc * 2);
  u16* kT    = (u16*)alloc((size_t)Hc * Hc * 2);
  u16* vTw   = (u16*)alloc((size_t)Hc * Hc * 2);
  u16* oT    = (u16*)alloc((size_t)Hc * Hc * 2);
  u16* intT  = (u16*)alloc((size_t)Hc * 4096 * 2);
  u16* outT  = (u16*)alloc((size_t)Hc * 4096 * 2);
  u16* fused = (u16*)alloc((size_t)8192 * Hc * 2);
  u16* qkact = (u16*)alloc((size_t)8192 * 2048 * 2);
  u16* scores= (u16*)alloc((size_t)Bc * Sc * Sc * 2);
  u16* vTact = (u16*)alloc((size_t)8192 * Hc * 2);
  u16* attn  = (u16*)alloc((size_t)8192 * Hc * 2);
  u16* h1    = (u16*)alloc((size_t)8192 * Hc * 2);
  u16* mid = qkact;  // FFN1 out [8192][4096] aliases qkact+scores (both dead)
  u16* ffo = attn;   // attn dead after o-proj

  if ((size_t)(w - (char*)d_ws) > ws_size) return;

  const dim3 tb32(32, 8);
  transpose_w4_k<<<dim3(32, 32, 4), tb32, 0, stream>>>(q_w, k_w, v_w, o_w, qT, kT, vTw, oT);
  transpose_w_k<<<dim3(4096 / 32, Hc / 32), tb32, 0, stream>>>(int_w, intT, Hc, 4096);
  transpose_w_k<<<dim3(Hc / 32, 4096 / 32), tb32, 0, stream>>>(out_w, outT, 4096, Hc);
  concat_bias_k<<<8, 256, 0, stream>>>(q_bias, k_bias, qk_bias);

  pool_partial_k<<<dim3(Hc / 256, 16, Bc), 256, 0, stream>>>(hs, amask, part);
  pool_final_k<<<Bc, 256, 0, stream>>>(part, amask, pooled);

  mrow_part_k<4><<<dim3(32, 8), 256, 0, stream>>>(pooled, cp_w, lin_part, Hc, Hc);
  mrow_reduce_k<true><<<16, 256, 0, stream>>>(lin_part, cp_b, hctx, Hc, 4, 8);
  ln_rows_k<<<Bc, 256, 0, stream>>>(hctx, cp_ln_g, cp_ln_b);
  mrow_part_k<4><<<dim3(32, 8), 256, 0, stream>>>(hctx, eph_w1, lin_part, Hc, Hc);
  mrow_reduce_k<true><<<16, 256, 0, stream>>>(lin_part, eph_b1, t1, Hc, 4, 8);
  mrow_part_k<4><<<dim3(2, 16), 256, 0, stream>>>(t1, eph_w2, lin_part, Hc, 64);
  mrow_reduce_k<false><<<1, 256, 0, stream>>>(lin_part, eph_b2, zlog, 64, 4, 16);
  gumbel_k<<<Bc, 64, 0, stream>>>(zlog, gn, codebook, zcodes);
  build_hwk_k<<<Bc * NEc, 256, 0, stream>>>(hctx, zcodes, hwk);
  mrow_part_k<16><<<dim3(64, 8), 256, 0, stream>>>(hwk, wk_w1, lin_part, Hc + CDc, 2048);
  mrow_reduce_k<true><<<128, 256, 0, stream>>>(lin_part, wk_b1, wkt1, 2048, 16, 8);
  mrow_part_k<16><<<dim3(4, 32), 256, 0, stream>>>(wkt1, wk_w2, lin_part, 2048, ODc);
  mrow_reduce_k<false><<<8, 256, 0, stream>>>(lin_part, wk_b2, outcome, ODc, 16, 32);
  mrow_part_k<4><<<dim3(4, 8), 256, 0, stream>>>(hctx, tp_w, lin_part, Hc, ODc);
  mrow_reduce_k<false><<<2, 256, 0, stream>>>(lin_part, nullptr, tvb, ODc, 4, 8);
  select_k<<<Bc, 128, 0, stream>>>(tvb, outcome, chosen);
  mrow_part_k<4><<<dim3(64, 2), 256, 0, stream>>>(chosen, film_w, lin_part, ODc, 2048);
  mrow_reduce_k<true><<<32, 256, 0, stream>>>(lin_part, film_b, gb, 2048, 4, 2);
  fuse_k<<<8192, 256, 0, stream>>>(hs, gb, fused);

  // merged q||k projection: [8192][1024] @ [2048][1024]^T -> [8192][2048]
  gemm8<1><<<dim3(256), 512, 0, stream>>>(fused, 0, Hc, qT, 0, Hc, qkact, 0, 2048,
                                          qk_bias, nullptr, 0, 1.f, 2048, Hc);
  // v written transposed ([H][B*S]) for the PV GEMM
  gemm_bt<9><<<dim3(512), 256, 0, stream>>>(fused, 0, Hc, vTw, 0, Hc, vTact, 0, 8192,
                                            v_bias, nullptr, 0, 1.f, 8192, Hc, Hc);
  // scores = q @ k^T / 32 (per batch)
  gemm8<0><<<dim3(64, 1, Bc), 512, 0, stream>>>(qkact, (long)Sc * 2048, 2048,
                                                qkact + 1024, (long)Sc * 2048, 2048,
                                                scores, (long)Sc * Sc, Sc,
                                                nullptr, nullptr, 0, 0.03125f, Sc, Hc);
  softmax_k<<<Bc * Sc, 256, 0, stream>>>(scores, amask);
  // attn_out = P @ V
  gemm8<0><<<dim3(32, 1, Bc), 512, 0, stream>>>(scores, (long)Sc * Sc, Sc,
                                                vTact, 2048, 8192,
                                                attn, (long)Sc * Hc, Hc,
                                                nullptr, nullptr, 0, 1.f, Hc, Sc);
  // o-proj + bias + residual(fused)
  gemm8<5><<<dim3(128), 512, 0, stream>>>(attn, 0, Hc, oT, 0, Hc, h1, 0, Hc,
                                          o_bias, fused, 0, 1.f, Hc, Hc);
  // FFN
  gemm8<3><<<dim3(512), 512, 0, stream>>>(h1, 0, Hc, intT, 0, Hc, mid, 0, 4096,
                                          int_b, nullptr, 0, 1.f, 4096, Hc);
  gemm8<1><<<dim3(128), 512, 0, stream>>>(mid, 0, 4096, outT, 0, 4096, ffo, 0, Hc,
                                          out_b, nullptr, 0, 1.f, Hc, 4096);
  final_ln_k<<<Bc * Sc, 256, 0, stream>>>(ffo, fused, ln_g, ln_b, outp);
}

// Round 8
// 561.054 us; speedup vs baseline: 1.6223x; 1.6223x over previous
//
#include <hip/hip_runtime.h>
#include <math.h>

#define DEVI __device__ __forceinline__

typedef unsigned short u16;
typedef __attribute__((ext_vector_type(4))) float f32x4;
typedef __attribute__((ext_vector_type(8))) short s16x8;
typedef __attribute__((ext_vector_type(4))) short s16x4;

constexpr int Bc = 4, Sc = 2048, Hc = 1024;
constexpr int NEc = 4, NCc = 16, CDc = 64, ODc = 128;
constexpr float TAUc = 0.5f, TEMPc = 0.07f, EPSc = 1e-5f;

DEVI float gelu_f(float x) { return 0.5f * x * (1.0f + erff(x * 0.7071067811865476f)); }

DEVI float bf2f(u16 u) { union { unsigned int i; float f; } v; v.i = ((unsigned int)u) << 16; return v.f; }
DEVI u16 f2bf(float f) {
  union { float f; unsigned int i; } v; v.f = f;
  unsigned int u = v.i;
  unsigned int r = (u + 0x7fffu + ((u >> 16) & 1u)) >> 16;
  return (u16)r;
}

DEVI float wred_sum(float v) {
  #pragma unroll
  for (int o = 32; o > 0; o >>= 1) v += __shfl_down(v, o);
  return v;
}
DEVI float wred_max(float v) {
  #pragma unroll
  for (int o = 32; o > 0; o >>= 1) v = fmaxf(v, __shfl_down(v, o));
  return v;
}

DEVI void gload16(const void* g, void* l) {
  __builtin_amdgcn_global_load_lds((const __attribute__((address_space(1))) void*)g,
                                   (__attribute__((address_space(3))) void*)l, 16, 0, 0);
}

// ---------------------------------------------------------------------------
// bf16 GEMM, C = act(scale*(A @ Bt^T) + bias) (+ residual), m97-style 128x128x32
// with LDS-staged, fully-coalesced epilogue (16B/lane row stores).
// A: [M][K] bf16 row-major. Bt: [N][K] bf16 row-major (i.e. B transposed).
// EPI bits: 1=bias, 2=gelu, 4=residual add, 8=transposed store.
// NOTE (rounds 5-7): the 256x256 8-phase port ("gemm8") consistently compiled
// to VGPR_Count=128 with ~950 MB/dispatch scratch traffic (426 us vs this
// kernel's 110 us on FFN1) regardless of __launch_bounds__(512,{1,2}) or
// amdgpu_waves_per_eu(2,2). Reverted to this verified structure (559 us total).
// ---------------------------------------------------------------------------
template<int EPI>
__global__ __launch_bounds__(256, 3) void gemm_bt(
    const u16* __restrict__ A, long sAz, int lda,
    const u16* __restrict__ Bt, long sBz, int ldb,
    u16* __restrict__ C, long sCz, int ldc,
    const float* __restrict__ bias,
    const u16* __restrict__ resid, long sRz,
    float scale, int M, int N, int K)
{
  const int bz = blockIdx.z;
  A += (long)bz * sAz; Bt += (long)bz * sBz; C += (long)bz * sCz;
  if (EPI & 4) resid += (long)bz * sRz;

  // XCD-aware bijective swizzle (all grids used are %8==0)
  int bid = blockIdx.x;
  const int nwg = gridDim.x;
  if ((nwg & 7) == 0) bid = ((bid & 7) * (nwg >> 3)) + (bid >> 3);

  const int nTn = N >> 7;
  const int tm = bid / nTn, tn = bid % nTn;
  const int tid = threadIdx.x;
  const int wid = tid >> 6, lane = tid & 63;
  const int wr = wid >> 1, wc = wid & 1;
  const int l15 = lane & 15, l4 = lane >> 4;

  __shared__ u16 smem[9216];          // 18 KB: As(8K) + Bs(8K); epilogue aliases
  u16* As = smem;
  u16* Bs = smem + 4096;

  f32x4 acc[4][4];
  #pragma unroll
  for (int i = 0; i < 4; ++i)
    #pragma unroll
    for (int j = 0; j < 4; ++j) acc[i][j] = f32x4{0.f, 0.f, 0.f, 0.f};

  const int srow = (wid << 5) + (lane >> 2);   // wave covers rows [wid*32, wid*32+32)
  const int scol = (lane & 3) << 3;
  const u16* aS = A + (long)(tm * 128 + srow) * lda + scol;
  const u16* bS = Bt + (long)(tn * 128 + srow) * ldb + scol;
  const long aStep16 = (long)16 * lda;
  const long bStep16 = (long)16 * ldb;
  u16* aD = &As[wid * 32 * 32];
  u16* bD = &Bs[wid * 32 * 32];

  for (int k0 = 0; k0 < K; k0 += 32) {
    gload16(aS, aD);
    gload16(aS + aStep16, aD + 16 * 32);
    gload16(bS, bD);
    gload16(bS + bStep16, bD + 16 * 32);
    __syncthreads();   // compiler drains vmcnt before barrier
    s16x8 af[4], bfr[4];
    #pragma unroll
    for (int i = 0; i < 4; ++i) {
      const int row = (wr << 6) + (i << 4) + l15;
      af[i] = *(const s16x8*)&As[(row << 5) + (l4 << 3)];
    }
    #pragma unroll
    for (int j = 0; j < 4; ++j) {
      const int col = (wc << 6) + (j << 4) + l15;
      bfr[j] = *(const s16x8*)&Bs[(col << 5) + (l4 << 3)];
    }
    #pragma unroll
    for (int i = 0; i < 4; ++i)
      #pragma unroll
      for (int j = 0; j < 4; ++j)
        acc[i][j] = __builtin_amdgcn_mfma_f32_16x16x32_bf16(af[i], bfr[j], acc[i][j], 0, 0, 0);
    __syncthreads();
    aS += 32; bS += 32;
  }
  // all gload_lds drained (vmcnt(0) before last barrier) -> smem reusable

  if (!(EPI & 8)) {
    // ---- normal store: two row-half passes through LDS, coalesced 16B stores
    u16 (*Cs)[128] = (u16(*)[128])smem;   // 64 x 128 bf16 = 16 KB
    #pragma unroll
    for (int p = 0; p < 2; ++p) {
      if (wr == p) {
        #pragma unroll
        for (int j = 0; j < 4; ++j) {
          const int c = (wc << 6) + (j << 4) + l15;
          const float bv = (EPI & 1) ? bias[tn * 128 + c] : 0.f;
          #pragma unroll
          for (int i = 0; i < 4; ++i) {
            const int lr = (i << 4) + (l4 << 2);
            #pragma unroll
            for (int r = 0; r < 4; ++r) {
              float v = acc[i][j][r] * scale + bv;
              if (EPI & 2) v = gelu_f(v);
              Cs[lr + r][c] = f2bf(v);
            }
          }
        }
      }
      __syncthreads();
      #pragma unroll
      for (int it = 0; it < 4; ++it) {
        const int row = (tid >> 4) + (it << 4);
        const int chunk = tid & 15;
        const long Gr = tm * 128 + (p << 6) + row;
        const int col0 = tn * 128 + (chunk << 3);
        s16x8 cv = *(s16x8*)&Cs[row][chunk << 3];
        if (EPI & 4) {
          const s16x8 rv = *(const s16x8*)&resid[Gr * ldc + col0];
          #pragma unroll
          for (int e = 0; e < 8; ++e)
            cv[e] = (short)f2bf(bf2f((u16)cv[e]) + bf2f((u16)rv[e]));
        }
        *(s16x8*)&C[Gr * ldc + col0] = cv;
      }
      if (p == 0) __syncthreads();
    }
  } else {
    // ---- transposed store: two col-half passes, LDS transpose, coalesced stores
    u16 (*Ct)[136] = (u16(*)[136])smem;   // 64 x (128+8 pad) bf16 = 17408 B
    #pragma unroll
    for (int p = 0; p < 2; ++p) {
      if (wc == p) {
        #pragma unroll
        for (int j = 0; j < 4; ++j) {
          const int lc = (j << 4) + l15;
          const float bv = (EPI & 1) ? bias[tn * 128 + (p << 6) + lc] : 0.f;
          #pragma unroll
          for (int i = 0; i < 4; ++i) {
            const int row_lo = (wr << 6) + (i << 4) + (l4 << 2);
            s16x4 pk;
            #pragma unroll
            for (int r = 0; r < 4; ++r) {
              float v = acc[i][j][r] * scale + bv;
              if (EPI & 2) v = gelu_f(v);
              pk[r] = (short)f2bf(v);
            }
            *(s16x4*)&Ct[lc][row_lo] = pk;
          }
        }
      }
      __syncthreads();
      #pragma unroll
      for (int it = 0; it < 4; ++it) {
        const int lc = (tid >> 4) + (it << 4);
        const int chunk = tid & 15;
        const long Gc = tn * 128 + (p << 6) + lc;
        const int col0 = tm * 128 + (chunk << 3);
        s16x8 cv = *(s16x8*)&Ct[lc][chunk << 3];
        *(s16x8*)&C[Gc * ldc + col0] = cv;
      }
      if (p == 0) __syncthreads();
    }
  }
}

// ---------------------------------------------------------------------------
// weight transpose fp32 [K][N] -> bf16 [N][K]
// ---------------------------------------------------------------------------
__global__ void transpose_w_k(const float* __restrict__ in, u16* __restrict__ out, int K, int N) {
  __shared__ float t[32][33];
  const int n0 = blockIdx.x << 5, k0 = blockIdx.y << 5;
  const int tx = threadIdx.x, ty = threadIdx.y;
  #pragma unroll
  for (int i = 0; i < 32; i += 8)
    t[ty + i][tx] = in[(long)(k0 + ty + i) * N + n0 + tx];
  __syncthreads();
  #pragma unroll
  for (int i = 0; i < 32; i += 8)
    out[(long)(n0 + ty + i) * K + k0 + tx] = f2bf(t[tx][ty + i]);
}

// combined transpose for four 1024x1024 weights (q,k,v,o)
__global__ void transpose_w4_k(const float* __restrict__ w0, const float* __restrict__ w1,
                               const float* __restrict__ w2, const float* __restrict__ w3,
                               u16* __restrict__ o0, u16* __restrict__ o1,
                               u16* __restrict__ o2, u16* __restrict__ o3) {
  const int z = blockIdx.z;
  const float* in = (z == 0) ? w0 : (z == 1) ? w1 : (z == 2) ? w2 : w3;
  u16* out = (z == 0) ? o0 : (z == 1) ? o1 : (z == 2) ? o2 : o3;
  __shared__ float t[32][33];
  const int n0 = blockIdx.x << 5, k0 = blockIdx.y << 5;
  const int tx = threadIdx.x, ty = threadIdx.y;
  #pragma unroll
  for (int i = 0; i < 32; i += 8)
    t[ty + i][tx] = in[(long)(k0 + ty + i) * Hc + n0 + tx];
  __syncthreads();
  #pragma unroll
  for (int i = 0; i < 32; i += 8)
    out[(long)(n0 + ty + i) * Hc + k0 + tx] = f2bf(t[tx][ty + i]);
}

__global__ void concat_bias_k(const float* __restrict__ a, const float* __restrict__ b,
                              float* __restrict__ o) {
  const int i = (blockIdx.x << 8) + threadIdx.x;
  o[i] = (i < Hc) ? a[i] : b[i - Hc];
}

// ---------------------------------------------------------------------------
// masked mean pool (deterministic 2-phase)
// ---------------------------------------------------------------------------
__global__ void pool_partial_k(const float* __restrict__ hs, const int* __restrict__ mask,
                               float* __restrict__ part) {
  const int h = (blockIdx.x << 8) + threadIdx.x;
  const int c = blockIdx.y, b = blockIdx.z;
  const int s0 = c * (Sc / 16);
  float acc = 0.f;
  for (int i = 0; i < Sc / 16; ++i) {
    const int s = s0 + i;
    acc += hs[((long)b * Sc + s) * Hc + h] * (float)mask[b * Sc + s];
  }
  part[((b << 4) + c) * Hc + h] = acc;
}

__global__ void pool_final_k(const float* __restrict__ part, const int* __restrict__ mask,
                             float* __restrict__ pooled) {
  const int b = blockIdx.x;
  __shared__ float red[4];
  __shared__ float denom_s;
  float d = 0.f;
  for (int i = threadIdx.x; i < Sc; i += 256) d += (float)mask[b * Sc + i];
  d = wred_sum(d);
  if ((threadIdx.x & 63) == 0) red[threadIdx.x >> 6] = d;
  __syncthreads();
  if (threadIdx.x == 0) denom_s = red[0] + red[1] + red[2] + red[3] + 1e-8f;
  __syncthreads();
  const float inv = 1.f / denom_s;
  for (int h = threadIdx.x; h < Hc; h += 256) {
    float s = 0.f;
    #pragma unroll
    for (int c = 0; c < 16; ++c) s += part[((b << 4) + c) * Hc + h];
    pooled[b * Hc + h] = s * inv;
  }
}

// ---------------------------------------------------------------------------
// split-K multi-row linear, stage 1: partial sums.
// ---------------------------------------------------------------------------
template<int R>
__global__ void mrow_part_k(const float* __restrict__ in, const float* __restrict__ W,
                            float* __restrict__ part, int K, int N) {
  const int t = threadIdx.x;
  const int jj = t & 31;
  const int j = (blockIdx.x << 5) + jj;
  const int ks = t >> 5;            // 0..7
  const int nchunk = gridDim.y;
  const int Kc = K / (nchunk << 3);
  const int k0 = ((blockIdx.y << 3) + ks) * Kc;
  float acc[R];
  #pragma unroll
  for (int r = 0; r < R; ++r) acc[r] = 0.f;
  for (int k = k0; k < k0 + Kc; ++k) {
    const float wv = W[(long)k * N + j];
    #pragma unroll
    for (int r = 0; r < R; ++r) acc[r] = fmaf(in[r * K + k], wv, acc[r]);
  }
  __shared__ float sm[8][R][32];
  #pragma unroll
  for (int r = 0; r < R; ++r) sm[ks][r][jj] = acc[r];
  __syncthreads();
  for (int idx = t; idx < R * 32; idx += 256) {
    const int r = idx >> 5, j2 = idx & 31;
    float s = 0.f;
    #pragma unroll
    for (int q = 0; q < 8; ++q) s += sm[q][r][j2];
    part[(long)(blockIdx.y * R + r) * N + (blockIdx.x << 5) + j2] = s;
  }
}

// stage 2: fixed-order reduce over chunks + bias + activation (deterministic)
template<bool GELU>
__global__ void mrow_reduce_k(const float* __restrict__ part, const float* __restrict__ bias,
                              float* __restrict__ out, int N, int R, int nchunk) {
  const int idx = (blockIdx.x << 8) + threadIdx.x;
  if (idx >= R * N) return;
  const int r = idx / N, j = idx - r * N;
  float s = 0.f;
  for (int c = 0; c < nchunk; ++c) s += part[(long)(c * R + r) * N + j];
  if (bias) s += bias[j];
  if (GELU) s = gelu_f(s);
  out[(long)r * N + j] = s;
}

// in-place LayerNorm over rows of length 1024
__global__ void ln_rows_k(float* __restrict__ x, const float* __restrict__ g,
                          const float* __restrict__ b) {
  const long base = (long)blockIdx.x * Hc;
  __shared__ float red[4];
  float v[4]; float s = 0.f;
  #pragma unroll
  for (int i = 0; i < 4; ++i) { v[i] = x[base + threadIdx.x + (i << 8)]; s += v[i]; }
  s = wred_sum(s);
  if ((threadIdx.x & 63) == 0) red[threadIdx.x >> 6] = s;
  __syncthreads();
  const float mean = (red[0] + red[1] + red[2] + red[3]) * (1.f / Hc);
  float q = 0.f;
  #pragma unroll
  for (int i = 0; i < 4; ++i) { const float d2 = v[i] - mean; q += d2 * d2; }
  __syncthreads();
  q = wred_sum(q);
  if ((threadIdx.x & 63) == 0) red[threadIdx.x >> 6] = q;
  __syncthreads();
  const float var = (red[0] + red[1] + red[2] + red[3]) * (1.f / Hc);
  const float inv = rsqrtf(var + EPSc);
  #pragma unroll
  for (int i = 0; i < 4; ++i) {
    const int col = threadIdx.x + (i << 8);
    x[base + col] = (v[i] - mean) * inv * g[col] + b[col];
  }
}

// gumbel one-hot -> code rows (z_soft == y_hard numerically)
__global__ void gumbel_k(const float* __restrict__ z, const float* __restrict__ gn,
                         const float* __restrict__ cb, float* __restrict__ zcodes) {
  const int b = blockIdx.x, t = threadIdx.x;
  if (t >= NEc) return;
  const float* zp = z + b * (NEc * NCc) + t * NCc;
  const float* gp = gn + (b * NEc + t) * NCc;
  int best = 0; float bv = -3.4e38f;
  for (int c2 = 0; c2 < NCc; ++c2) {
    const float val = (zp[c2] + gp[c2]) * (1.f / TAUc);
    if (val > bv) { bv = val; best = c2; }   // strict > == jnp.argmax first-max
  }
  for (int d2 = 0; d2 < CDc; ++d2)
    zcodes[(b * NEc + t) * CDc + d2] = cb[best * CDc + d2];
}

__global__ void build_hwk_k(const float* __restrict__ hctx, const float* __restrict__ zcodes,
                            float* __restrict__ hwk) {
  const int r = blockIdx.x;
  const int b = r >> 2;
  for (int i = threadIdx.x; i < Hc + CDc; i += 256)
    hwk[r * (Hc + CDc) + i] = (i < Hc) ? hctx[b * Hc + i] : zcodes[r * CDc + (i - Hc)];
}

// tv normalize + info gain + argmax select -> chosen
__global__ void select_k(const float* __restrict__ tv, const float* __restrict__ outc,
                         float* __restrict__ chosen) {
  const int b = blockIdx.x, t = threadIdx.x;   // 128 threads
  __shared__ float red[2];
  __shared__ float ig[NEc];
  __shared__ int bestIdx;
  const float x = tv[b * ODc + t];
  float ss = wred_sum(x * x);
  if ((t & 63) == 0) red[t >> 6] = ss;
  __syncthreads();
  float nrm = fmaxf(sqrtf(red[0] + red[1]), 1e-12f);
  const float tvn = x / nrm;
  __syncthreads();
  for (int ne = 0; ne < NEc; ++ne) {
    const float o = outc[(b * NEc + ne) * ODc + t];
    float a = wred_sum(o * o);
    float d2 = wred_sum(o * tvn);
    if ((t & 63) == 0) red[t >> 6] = a;
    __syncthreads();
    const float no = sqrtf(red[0] + red[1]);
    __syncthreads();
    if ((t & 63) == 0) red[t >> 6] = d2;
    __syncthreads();
    const float dd = red[0] + red[1];
    if (t == 0) ig[ne] = dd / fmaxf(no, 1e-12f) * (1.f / TEMPc);
    __syncthreads();
  }
  if (t == 0) {
    int bi = 0; float bvv = ig[0];
    for (int ne = 1; ne < NEc; ++ne) if (ig[ne] > bvv) { bvv = ig[ne]; bi = ne; }
    bestIdx = bi;
  }
  __syncthreads();
  chosen[b * ODc + t] = outc[(b * NEc + bestIdx) * ODc + t];
}

// fused = gamma*hidden + beta  (bf16 out)
__global__ void fuse_k(const float* __restrict__ hs, const float* __restrict__ gb,
                       u16* __restrict__ fused) {
  const long i = (((long)blockIdx.x << 8) + threadIdx.x) << 2;
  const int h = (int)(i & (Hc - 1));
  const int b = (int)(i >> 21);   // / (S*H) = 2^21
  const float4 xv = *(const float4*)(hs + i);
  const float* gp = gb + b * 2048;
  s16x4 pk = { (short)f2bf(fmaf(gp[h + 0], xv.x, gp[Hc + h + 0])),
               (short)f2bf(fmaf(gp[h + 1], xv.y, gp[Hc + h + 1])),
               (short)f2bf(fmaf(gp[h + 2], xv.z, gp[Hc + h + 2])),
               (short)f2bf(fmaf(gp[h + 3], xv.w, gp[Hc + h + 3])) };
  *(s16x4*)(fused + i) = pk;
}

// row softmax over 2048 bf16 scores (in-place), with attention mask
__global__ void softmax_k(u16* __restrict__ sc, const int* __restrict__ mask) {
  const long base = (long)blockIdx.x * Sc;
  const int b = blockIdx.x / Sc;
  __shared__ float red[4];
  float x[8];
  float mx = -3.0e38f;
  #pragma unroll
  for (int i = 0; i < 8; ++i) {
    const int col = threadIdx.x + (i << 8);
    float v = bf2f(sc[base + col]);
    if (mask[b * Sc + col] == 0) v = -3.0e38f;
    x[i] = v;
    mx = fmaxf(mx, v);
  }
  mx = wred_max(mx);
  if ((threadIdx.x & 63) == 0) red[threadIdx.x >> 6] = mx;
  __syncthreads();
  mx = fmaxf(fmaxf(red[0], red[1]), fmaxf(red[2], red[3]));
  float sum = 0.f;
  #pragma unroll
  for (int i = 0; i < 8; ++i) { x[i] = __expf(x[i] - mx); sum += x[i]; }
  __syncthreads();
  sum = wred_sum(sum);
  if ((threadIdx.x & 63) == 0) red[threadIdx.x >> 6] = sum;
  __syncthreads();
  const float inv = 1.f / (red[0] + red[1] + red[2] + red[3]);
  #pragma unroll
  for (int i = 0; i < 8; ++i)
    sc[base + threadIdx.x + (i << 8)] = f2bf(x[i] * inv);
}

// out = LN(ff + fused) * g + b   (fp32 out)
__global__ void final_ln_k(const u16* __restrict__ ff, const u16* __restrict__ fused,
                           const float* __restrict__ g, const float* __restrict__ b,
                           float* __restrict__ out) {
  const long base = (long)blockIdx.x * Hc;
  __shared__ float red[4];
  float v[4]; float s = 0.f;
  #pragma unroll
  for (int i = 0; i < 4; ++i) {
    const int col = threadIdx.x + (i << 8);
    v[i] = bf2f(ff[base + col]) + bf2f(fused[base + col]);
    s += v[i];
  }
  s = wred_sum(s);
  if ((threadIdx.x & 63) == 0) red[threadIdx.x >> 6] = s;
  __syncthreads();
  const float mean = (red[0] + red[1] + red[2] + red[3]) * (1.f / Hc);
  float q = 0.f;
  #pragma unroll
  for (int i = 0; i < 4; ++i) { const float d2 = v[i] - mean; q += d2 * d2; }
  __syncthreads();
  q = wred_sum(q);
  if ((threadIdx.x & 63) == 0) red[threadIdx.x >> 6] = q;
  __syncthreads();
  const float var = (red[0] + red[1] + red[2] + red[3]) * (1.f / Hc);
  const float inv = rsqrtf(var + EPSc);
  #pragma unroll
  for (int i = 0; i < 4; ++i) {
    const int col = threadIdx.x + (i << 8);
    out[base + col] = (v[i] - mean) * inv * g[col] + b[col];
  }
}

// ---------------------------------------------------------------------------
extern "C" void kernel_launch(void* const* d_in, const int* in_sizes, int n_in,
                              void* d_out, int out_size, void* d_ws, size_t ws_size,
                              hipStream_t stream) {
  const float* hs       = (const float*)d_in[0];
  const int*   amask    = (const int*)d_in[1];
  const float* gn       = (const float*)d_in[2];
  const float* cp_w     = (const float*)d_in[3];
  const float* cp_b     = (const float*)d_in[4];
  const float* cp_ln_g  = (const float*)d_in[5];
  const float* cp_ln_b  = (const float*)d_in[6];
  const float* eph_w1   = (const float*)d_in[7];
  const float* eph_b1   = (const float*)d_in[8];
  const float* eph_w2   = (const float*)d_in[9];
  const float* eph_b2   = (const float*)d_in[10];
  const float* codebook = (const float*)d_in[11];
  const float* wk_w1    = (const float*)d_in[12];
  const float* wk_b1    = (const float*)d_in[13];
  const float* wk_w2    = (const float*)d_in[14];
  const float* wk_b2    = (const float*)d_in[15];
  const float* tp_w     = (const float*)d_in[16];
  const float* film_w   = (const float*)d_in[17];
  const float* film_b   = (const float*)d_in[18];
  const float* q_w      = (const float*)d_in[19];
  const float* q_bias   = (const float*)d_in[20];
  const float* k_w      = (const float*)d_in[21];
  const float* k_bias   = (const float*)d_in[22];
  const float* v_w      = (const float*)d_in[23];
  const float* v_bias   = (const float*)d_in[24];
  const float* o_w      = (const float*)d_in[25];
  const float* o_bias   = (const float*)d_in[26];
  const float* int_w    = (const float*)d_in[27];
  const float* int_b    = (const float*)d_in[28];
  const float* out_w    = (const float*)d_in[29];
  const float* out_b    = (const float*)d_in[30];
  const float* ln_g     = (const float*)d_in[31];
  const float* ln_b     = (const float*)d_in[32];
  float* outp = (float*)d_out;

  char* w = (char*)d_ws;
  auto alloc = [&](size_t bytes) -> char* {
    char* p = w; w += (bytes + 255) & ~(size_t)255; return p;
  };
  float* part    = (float*)alloc((size_t)Bc * 16 * Hc * 4);
  float* pooled  = (float*)alloc((size_t)Bc * Hc * 4);
  float* hctx    = (float*)alloc((size_t)Bc * Hc * 4);
  float* t1      = (float*)alloc((size_t)Bc * Hc * 4);
  float* zlog    = (float*)alloc((size_t)Bc * 64 * 4);
  float* zcodes  = (float*)alloc((size_t)Bc * NEc * CDc * 4);
  float* hwk     = (float*)alloc((size_t)16 * (Hc + CDc) * 4);
  float* wkt1    = (float*)alloc((size_t)16 * 2048 * 4);
  float* outcome = (float*)alloc((size_t)16 * ODc * 4);
  float* tvb     = (float*)alloc((size_t)Bc * ODc * 4);
  float* chosen  = (float*)alloc((size_t)Bc * ODc * 4);
  float* gb      = (float*)alloc((size_t)Bc * 2048 * 4);
  float* lin_part= (float*)alloc((size_t)1024 * 1024);   // 1 MB split-K partials
  float* qk_bias = (float*)alloc((size_t)2048 * 4);
  u16* qT    = (u16*)alloc((size_t)Hc * Hc * 2);         // qT,kT contiguous -> merged Bt
  u16* kT    = (u16*)alloc((size_t)Hc * Hc * 2);
  u16* vTw   = (u16*)alloc((size_t)Hc * Hc * 2);
  u16* oT    = (u16*)alloc((size_t)Hc * Hc * 2);
  u16* intT  = (u16*)alloc((size_t)Hc * 4096 * 2);
  u16* outT  = (u16*)alloc((size_t)Hc * 4096 * 2);
  u16* fused = (u16*)alloc((size_t)8192 * Hc * 2);
  u16* qkact = (u16*)alloc((size_t)8192 * 2048 * 2);     // q||k, ld 2048 (32 MB)
  u16* scores= (u16*)alloc((size_t)Bc * Sc * Sc * 2);    // 32 MB, right after qkact
  u16* vTact = (u16*)alloc((size_t)8192 * Hc * 2);
  u16* attn  = (u16*)alloc((size_t)8192 * Hc * 2);
  u16* h1    = (u16*)alloc((size_t)8192 * Hc * 2);
  u16* mid = qkact;  // FFN1 out [8192][4096] = qkact(32MB)+scores(32MB), both dead
  u16* ffo = attn;   // attn dead after o-proj

  if ((size_t)(w - (char*)d_ws) > ws_size) return;  // visible failure if ws too small

  const dim3 tb32(32, 8);
  transpose_w4_k<<<dim3(32, 32, 4), tb32, 0, stream>>>(q_w, k_w, v_w, o_w, qT, kT, vTw, oT);
  transpose_w_k<<<dim3(4096 / 32, Hc / 32), tb32, 0, stream>>>(int_w, intT, Hc, 4096);
  transpose_w_k<<<dim3(Hc / 32, 4096 / 32), tb32, 0, stream>>>(out_w, outT, 4096, Hc);
  concat_bias_k<<<8, 256, 0, stream>>>(q_bias, k_bias, qk_bias);

  pool_partial_k<<<dim3(Hc / 256, 16, Bc), 256, 0, stream>>>(hs, amask, part);
  pool_final_k<<<Bc, 256, 0, stream>>>(part, amask, pooled);

  // h_ctx = LN(gelu(pooled @ cp_w + cp_b))
  mrow_part_k<4><<<dim3(32, 8), 256, 0, stream>>>(pooled, cp_w, lin_part, Hc, Hc);
  mrow_reduce_k<true><<<16, 256, 0, stream>>>(lin_part, cp_b, hctx, Hc, 4, 8);
  ln_rows_k<<<Bc, 256, 0, stream>>>(hctx, cp_ln_g, cp_ln_b);
  // t1 = gelu(hctx @ eph_w1 + b1)
  mrow_part_k<4><<<dim3(32, 8), 256, 0, stream>>>(hctx, eph_w1, lin_part, Hc, Hc);
  mrow_reduce_k<true><<<16, 256, 0, stream>>>(lin_part, eph_b1, t1, Hc, 4, 8);
  // zlog = t1 @ eph_w2 + b2
  mrow_part_k<4><<<dim3(2, 16), 256, 0, stream>>>(t1, eph_w2, lin_part, Hc, 64);
  mrow_reduce_k<false><<<1, 256, 0, stream>>>(lin_part, eph_b2, zlog, 64, 4, 16);
  gumbel_k<<<Bc, 64, 0, stream>>>(zlog, gn, codebook, zcodes);
  build_hwk_k<<<Bc * NEc, 256, 0, stream>>>(hctx, zcodes, hwk);
  // wkt1 = gelu(hwk @ wk_w1 + b1)   (16 x 1088 x 2048)
  mrow_part_k<16><<<dim3(64, 8), 256, 0, stream>>>(hwk, wk_w1, lin_part, Hc + CDc, 2048);
  mrow_reduce_k<true><<<128, 256, 0, stream>>>(lin_part, wk_b1, wkt1, 2048, 16, 8);
  // outcome = wkt1 @ wk_w2 + b2    (16 x 2048 x 128)
  mrow_part_k<16><<<dim3(4, 32), 256, 0, stream>>>(wkt1, wk_w2, lin_part, 2048, ODc);
  mrow_reduce_k<false><<<8, 256, 0, stream>>>(lin_part, wk_b2, outcome, ODc, 16, 32);
  // tv = hctx @ tp_w
  mrow_part_k<4><<<dim3(4, 8), 256, 0, stream>>>(hctx, tp_w, lin_part, Hc, ODc);
  mrow_reduce_k<false><<<2, 256, 0, stream>>>(lin_part, nullptr, tvb, ODc, 4, 8);
  select_k<<<Bc, 128, 0, stream>>>(tvb, outcome, chosen);
  // gb = gelu(chosen @ film_w + film_b)  (4 x 128 x 2048)
  mrow_part_k<4><<<dim3(64, 2), 256, 0, stream>>>(chosen, film_w, lin_part, ODc, 2048);
  mrow_reduce_k<true><<<32, 256, 0, stream>>>(lin_part, film_b, gb, 2048, 4, 2);
  fuse_k<<<8192, 256, 0, stream>>>(hs, gb, fused);

  // merged q||k projection: [8192][1024] @ [2048][1024]^T -> [8192][2048]
  gemm_bt<1><<<dim3(1024), 256, 0, stream>>>(fused, 0, Hc, qT, 0, Hc, qkact, 0, 2048,
                                             qk_bias, nullptr, 0, 1.f, 8192, 2048, Hc);
  // v written transposed ([H][B*S]) for the PV GEMM
  gemm_bt<9><<<dim3(512), 256, 0, stream>>>(fused, 0, Hc, vTw, 0, Hc, vTact, 0, 8192,
                                            v_bias, nullptr, 0, 1.f, 8192, Hc, Hc);
  // scores = q @ k^T / 32  (per batch; q = qkact cols 0-1023, k = cols 1024-2047)
  gemm_bt<0><<<dim3(256, 1, Bc), 256, 0, stream>>>(qkact, (long)Sc * 2048, 2048,
                                                   qkact + 1024, (long)Sc * 2048, 2048,
                                                   scores, (long)Sc * Sc, Sc,
                                                   nullptr, nullptr, 0, 0.03125f, Sc, Sc, Hc);
  softmax_k<<<Bc * Sc, 256, 0, stream>>>(scores, amask);
  // attn_out = P @ V   (Bt = vTact slice per batch)
  gemm_bt<0><<<dim3(128, 1, Bc), 256, 0, stream>>>(scores, (long)Sc * Sc, Sc,
                                                   vTact, (long)Sc, 8192,
                                                   attn, (long)Sc * Hc, Hc,
                                                   nullptr, nullptr, 0, 1.f, Sc, Hc, Sc);
  // o-proj + bias + residual(fused) -> h1
  gemm_bt<5><<<dim3(512), 256, 0, stream>>>(attn, 0, Hc, oT, 0, Hc, h1, 0, Hc,
                                            o_bias, fused, 0, 1.f, 8192, Hc, Hc);
  // FFN
  gemm_bt<3><<<dim3(2048), 256, 0, stream>>>(h1, 0, Hc, intT, 0, Hc, mid, 0, 4096,
                                             int_b, nullptr, 0, 1.f, 8192, 4096, Hc);
  gemm_bt<1><<<dim3(512), 256, 0, stream>>>(mid, 0, 4096, outT, 0, 4096, ffo, 0, Hc,
                                            out_b, nullptr, 0, 1.f, 8192, Hc, 4096);
  final_ln_k<<<Bc * Sc, 256, 0, stream>>>(ffo, fused, ln_g, ln_b, outp);
}

// Round 9
// 492.315 us; speedup vs baseline: 1.8488x; 1.1396x over previous
//
#include <hip/hip_runtime.h>
#include <math.h>

#define DEVI __device__ __forceinline__

typedef unsigned short u16;
typedef __attribute__((ext_vector_type(4))) float f32x4;
typedef __attribute__((ext_vector_type(8))) short s16x8;
typedef __attribute__((ext_vector_type(4))) short s16x4;

constexpr int Bc = 4, Sc = 2048, Hc = 1024;
constexpr int NEc = 4, NCc = 16, CDc = 64, ODc = 128;
constexpr float TAUc = 0.5f, TEMPc = 0.07f, EPSc = 1e-5f;

DEVI float gelu_f(float x) { return 0.5f * x * (1.0f + erff(x * 0.7071067811865476f)); }

DEVI float bf2f(u16 u) { union { unsigned int i; float f; } v; v.i = ((unsigned int)u) << 16; return v.f; }
DEVI u16 f2bf(float f) {
  union { float f; unsigned int i; } v; v.f = f;
  unsigned int u = v.i;
  unsigned int r = (u + 0x7fffu + ((u >> 16) & 1u)) >> 16;
  return (u16)r;
}

DEVI float wred_sum(float v) {
  #pragma unroll
  for (int o = 32; o > 0; o >>= 1) v += __shfl_down(v, o);
  return v;
}
DEVI float wred_max(float v) {
  #pragma unroll
  for (int o = 32; o > 0; o >>= 1) v = fmaxf(v, __shfl_down(v, o));
  return v;
}

DEVI void gload16(const void* g, void* l) {
  __builtin_amdgcn_global_load_lds((const __attribute__((address_space(1))) void*)g,
                                   (__attribute__((address_space(3))) void*)l, 16, 0, 0);
}

// ---------------------------------------------------------------------------
// bf16 GEMM, C = act(scale*(A @ Bt^T) + bias) (+ residual), 128x128 tile,
// BK=64 (32 MFMA per barrier-pair vs 16 at BK=32 -> half the barrier-drain
// stalls), T2 XOR-swizzled LDS (rule #21: linear gload_lds dest + XOR'd
// GLOBAL source chunk + XOR'd ds_read slot; involution verified correct in
// rounds 5-7's gemm8). Lane->k fragment map identical to the verified m97
// kernel. Coalesced LDS-staged epilogue.
// EPI bits: 1=bias, 2=gelu, 4=residual add, 8=transposed store.
// NOTE (rounds 5-7): the 256x256 8-phase "gemm8" consistently compiled to
// VGPR_Count=128 + full acc spill (~950 MB scratch/dispatch) regardless of
// __launch_bounds__(512,{1,2}) / amdgpu_waves_per_eu(2,2) -> abandoned.
// ---------------------------------------------------------------------------
template<int EPI>
__global__ __launch_bounds__(256, 3) void gemm_bt(
    const u16* __restrict__ A, long sAz, int lda,
    const u16* __restrict__ Bt, long sBz, int ldb,
    u16* __restrict__ C, long sCz, int ldc,
    const float* __restrict__ bias,
    const u16* __restrict__ resid, long sRz,
    float scale, int M, int N, int K)
{
  const int bz = blockIdx.z;
  A += (long)bz * sAz; Bt += (long)bz * sBz; C += (long)bz * sCz;
  if (EPI & 4) resid += (long)bz * sRz;

  // XCD-aware bijective swizzle (all grids used are %8==0)
  int bid = blockIdx.x;
  const int nwg = gridDim.x;
  if ((nwg & 7) == 0) bid = ((bid & 7) * (nwg >> 3)) + (bid >> 3);

  const int nTn = N >> 7;
  const int tm = bid / nTn, tn = bid % nTn;
  const int tid = threadIdx.x;
  const int wid = tid >> 6, lane = tid & 63;
  const int wr = wid >> 1, wc = wid & 1;
  const int l15 = lane & 15, l4 = lane >> 4;

  __shared__ u16 smem[16384];         // 32 KB: As[128][64] + Bs[128][64]
  u16* As = smem;
  u16* Bs = smem + 8192;

  f32x4 acc[4][4];
  #pragma unroll
  for (int i = 0; i < 4; ++i)
    #pragma unroll
    for (int j = 0; j < 4; ++j) acc[i][j] = f32x4{0.f, 0.f, 0.f, 0.f};

  // staging: wave wid covers rows [wid*32, wid*32+32), 4 passes x 8 rows.
  // lane -> (row = lane>>3, slot = lane&7); LDS dest is wave-uniform base,
  // HW scatters lane*16B = row-major [8][64]. Global source chunk is
  // XOR-pre-swizzled: slot s of row r holds global chunk s^(r&7).
  const int srow8 = lane >> 3;                       // row-within-pass, == row&7
  const int scol = (((lane & 7) ^ srow8) << 3);      // swizzled source column
  const u16* aS = A + (long)(tm * 128 + (wid << 5) + srow8) * lda + scol;
  const u16* bS = Bt + (long)(tn * 128 + (wid << 5) + srow8) * ldb + scol;
  u16* aD = &As[wid * 2048];
  u16* bD = &Bs[wid * 2048];

  // ds_read slot for global chunk g = ks*4+l4 of row r: slot = g ^ (r&7);
  // fragment rows have row&7 == l15&7.
  const int x7 = l15 & 7;
  const int cx0 = ((l4 ^ x7) << 3);                  // ks=0
  const int cx1 = (((l4 + 4) ^ x7) << 3);            // ks=1

  for (int k0 = 0; k0 < K; k0 += 64) {
    #pragma unroll
    for (int L = 0; L < 4; ++L) {
      gload16(aS + (long)(L * 8) * lda, aD + L * 512);
      gload16(bS + (long)(L * 8) * ldb, bD + L * 512);
    }
    __syncthreads();   // compiler drains vmcnt before barrier
    #pragma unroll
    for (int ks = 0; ks < 2; ++ks) {
      const int cx = ks ? cx1 : cx0;
      s16x8 af[4], bfr[4];
      #pragma unroll
      for (int i = 0; i < 4; ++i)
        af[i] = *(const s16x8*)&As[((wr << 6) + (i << 4) + l15) * 64 + cx];
      #pragma unroll
      for (int j = 0; j < 4; ++j)
        bfr[j] = *(const s16x8*)&Bs[((wc << 6) + (j << 4) + l15) * 64 + cx];
      #pragma unroll
      for (int i = 0; i < 4; ++i)
        #pragma unroll
        for (int j = 0; j < 4; ++j)
          acc[i][j] = __builtin_amdgcn_mfma_f32_16x16x32_bf16(af[i], bfr[j], acc[i][j], 0, 0, 0);
    }
    __syncthreads();
    aS += 64; bS += 64;
  }
  // all gload_lds drained (vmcnt(0) before last barrier) -> smem reusable

  if (!(EPI & 8)) {
    // ---- normal store: two row-half passes through LDS, coalesced 16B stores
    u16 (*Cs)[128] = (u16(*)[128])smem;   // 64 x 128 bf16 = 16 KB
    #pragma unroll
    for (int p = 0; p < 2; ++p) {
      if (wr == p) {
        #pragma unroll
        for (int j = 0; j < 4; ++j) {
          const int c = (wc << 6) + (j << 4) + l15;
          const float bv = (EPI & 1) ? bias[tn * 128 + c] : 0.f;
          #pragma unroll
          for (int i = 0; i < 4; ++i) {
            const int lr = (i << 4) + (l4 << 2);
            #pragma unroll
            for (int r = 0; r < 4; ++r) {
              float v = acc[i][j][r] * scale + bv;
              if (EPI & 2) v = gelu_f(v);
              Cs[lr + r][c] = f2bf(v);
            }
          }
        }
      }
      __syncthreads();
      #pragma unroll
      for (int it = 0; it < 4; ++it) {
        const int row = (tid >> 4) + (it << 4);
        const int chunk = tid & 15;
        const long Gr = tm * 128 + (p << 6) + row;
        const int col0 = tn * 128 + (chunk << 3);
        s16x8 cv = *(s16x8*)&Cs[row][chunk << 3];
        if (EPI & 4) {
          const s16x8 rv = *(const s16x8*)&resid[Gr * ldc + col0];
          #pragma unroll
          for (int e = 0; e < 8; ++e)
            cv[e] = (short)f2bf(bf2f((u16)cv[e]) + bf2f((u16)rv[e]));
        }
        *(s16x8*)&C[Gr * ldc + col0] = cv;
      }
      if (p == 0) __syncthreads();
    }
  } else {
    // ---- transposed store: two col-half passes, LDS transpose, coalesced stores
    u16 (*Ct)[136] = (u16(*)[136])smem;   // 64 x (128+8 pad) bf16 = 17408 B
    #pragma unroll
    for (int p = 0; p < 2; ++p) {
      if (wc == p) {
        #pragma unroll
        for (int j = 0; j < 4; ++j) {
          const int lc = (j << 4) + l15;
          const float bv = (EPI & 1) ? bias[tn * 128 + (p << 6) + lc] : 0.f;
          #pragma unroll
          for (int i = 0; i < 4; ++i) {
            const int row_lo = (wr << 6) + (i << 4) + (l4 << 2);
            s16x4 pk;
            #pragma unroll
            for (int r = 0; r < 4; ++r) {
              float v = acc[i][j][r] * scale + bv;
              if (EPI & 2) v = gelu_f(v);
              pk[r] = (short)f2bf(v);
            }
            *(s16x4*)&Ct[lc][row_lo] = pk;
          }
        }
      }
      __syncthreads();
      #pragma unroll
      for (int it = 0; it < 4; ++it) {
        const int lc = (tid >> 4) + (it << 4);
        const int chunk = tid & 15;
        const long Gc = tn * 128 + (p << 6) + lc;
        const int col0 = tm * 128 + (chunk << 3);
        s16x8 cv = *(s16x8*)&Ct[lc][chunk << 3];
        *(s16x8*)&C[Gc * ldc + col0] = cv;
      }
      if (p == 0) __syncthreads();
    }
  }
}

// ---------------------------------------------------------------------------
// weight transpose fp32 [K][N] -> bf16 [N][K]
// ---------------------------------------------------------------------------
__global__ void transpose_w_k(const float* __restrict__ in, u16* __restrict__ out, int K, int N) {
  __shared__ float t[32][33];
  const int n0 = blockIdx.x << 5, k0 = blockIdx.y << 5;
  const int tx = threadIdx.x, ty = threadIdx.y;
  #pragma unroll
  for (int i = 0; i < 32; i += 8)
    t[ty + i][tx] = in[(long)(k0 + ty + i) * N + n0 + tx];
  __syncthreads();
  #pragma unroll
  for (int i = 0; i < 32; i += 8)
    out[(long)(n0 + ty + i) * K + k0 + tx] = f2bf(t[tx][ty + i]);
}

// combined transpose for four 1024x1024 weights (q,k,v,o)
__global__ void transpose_w4_k(const float* __restrict__ w0, const float* __restrict__ w1,
                               const float* __restrict__ w2, const float* __restrict__ w3,
                               u16* __restrict__ o0, u16* __restrict__ o1,
                               u16* __restrict__ o2, u16* __restrict__ o3) {
  const int z = blockIdx.z;
  const float* in = (z == 0) ? w0 : (z == 1) ? w1 : (z == 2) ? w2 : w3;
  u16* out = (z == 0) ? o0 : (z == 1) ? o1 : (z == 2) ? o2 : o3;
  __shared__ float t[32][33];
  const int n0 = blockIdx.x << 5, k0 = blockIdx.y << 5;
  const int tx = threadIdx.x, ty = threadIdx.y;
  #pragma unroll
  for (int i = 0; i < 32; i += 8)
    t[ty + i][tx] = in[(long)(k0 + ty + i) * Hc + n0 + tx];
  __syncthreads();
  #pragma unroll
  for (int i = 0; i < 32; i += 8)
    out[(long)(n0 + ty + i) * Hc + k0 + tx] = f2bf(t[tx][ty + i]);
}

__global__ void concat_bias_k(const float* __restrict__ a, const float* __restrict__ b,
                              float* __restrict__ o) {
  const int i = (blockIdx.x << 8) + threadIdx.x;
  o[i] = (i < Hc) ? a[i] : b[i - Hc];
}

// ---------------------------------------------------------------------------
// masked mean pool (deterministic 2-phase)
// ---------------------------------------------------------------------------
__global__ void pool_partial_k(const float* __restrict__ hs, const int* __restrict__ mask,
                               float* __restrict__ part) {
  const int h = (blockIdx.x << 8) + threadIdx.x;
  const int c = blockIdx.y, b = blockIdx.z;
  const int s0 = c * (Sc / 16);
  float acc = 0.f;
  for (int i = 0; i < Sc / 16; ++i) {
    const int s = s0 + i;
    acc += hs[((long)b * Sc + s) * Hc + h] * (float)mask[b * Sc + s];
  }
  part[((b << 4) + c) * Hc + h] = acc;
}

__global__ void pool_final_k(const float* __restrict__ part, const int* __restrict__ mask,
                             float* __restrict__ pooled) {
  const int b = blockIdx.x;
  __shared__ float red[4];
  __shared__ float denom_s;
  float d = 0.f;
  for (int i = threadIdx.x; i < Sc; i += 256) d += (float)mask[b * Sc + i];
  d = wred_sum(d);
  if ((threadIdx.x & 63) == 0) red[threadIdx.x >> 6] = d;
  __syncthreads();
  if (threadIdx.x == 0) denom_s = red[0] + red[1] + red[2] + red[3] + 1e-8f;
  __syncthreads();
  const float inv = 1.f / denom_s;
  for (int h = threadIdx.x; h < Hc; h += 256) {
    float s = 0.f;
    #pragma unroll
    for (int c = 0; c < 16; ++c) s += part[((b << 4) + c) * Hc + h];
    pooled[b * Hc + h] = s * inv;
  }
}

// ---------------------------------------------------------------------------
// split-K multi-row linear, stage 1: partial sums.
// ---------------------------------------------------------------------------
template<int R>
__global__ void mrow_part_k(const float* __restrict__ in, const float* __restrict__ W,
                            float* __restrict__ part, int K, int N) {
  const int t = threadIdx.x;
  const int jj = t & 31;
  const int j = (blockIdx.x << 5) + jj;
  const int ks = t >> 5;            // 0..7
  const int nchunk = gridDim.y;
  const int Kc = K / (nchunk << 3);
  const int k0 = ((blockIdx.y << 3) + ks) * Kc;
  float acc[R];
  #pragma unroll
  for (int r = 0; r < R; ++r) acc[r] = 0.f;
  for (int k = k0; k < k0 + Kc; ++k) {
    const float wv = W[(long)k * N + j];
    #pragma unroll
    for (int r = 0; r < R; ++r) acc[r] = fmaf(in[r * K + k], wv, acc[r]);
  }
  __shared__ float sm[8][R][32];
  #pragma unroll
  for (int r = 0; r < R; ++r) sm[ks][r][jj] = acc[r];
  __syncthreads();
  for (int idx = t; idx < R * 32; idx += 256) {
    const int r = idx >> 5, j2 = idx & 31;
    float s = 0.f;
    #pragma unroll
    for (int q = 0; q < 8; ++q) s += sm[q][r][j2];
    part[(long)(blockIdx.y * R + r) * N + (blockIdx.x << 5) + j2] = s;
  }
}

// stage 2: fixed-order reduce over chunks + bias + activation (deterministic)
template<bool GELU>
__global__ void mrow_reduce_k(const float* __restrict__ part, const float* __restrict__ bias,
                              float* __restrict__ out, int N, int R, int nchunk) {
  const int idx = (blockIdx.x << 8) + threadIdx.x;
  if (idx >= R * N) return;
  const int r = idx / N, j = idx - r * N;
  float s = 0.f;
  for (int c = 0; c < nchunk; ++c) s += part[(long)(c * R + r) * N + j];
  if (bias) s += bias[j];
  if (GELU) s = gelu_f(s);
  out[(long)r * N + j] = s;
}

// in-place LayerNorm over rows of length 1024
__global__ void ln_rows_k(float* __restrict__ x, const float* __restrict__ g,
                          const float* __restrict__ b) {
  const long base = (long)blockIdx.x * Hc;
  __shared__ float red[4];
  float v[4]; float s = 0.f;
  #pragma unroll
  for (int i = 0; i < 4; ++i) { v[i] = x[base + threadIdx.x + (i << 8)]; s += v[i]; }
  s = wred_sum(s);
  if ((threadIdx.x & 63) == 0) red[threadIdx.x >> 6] = s;
  __syncthreads();
  const float mean = (red[0] + red[1] + red[2] + red[3]) * (1.f / Hc);
  float q = 0.f;
  #pragma unroll
  for (int i = 0; i < 4; ++i) { const float d2 = v[i] - mean; q += d2 * d2; }
  __syncthreads();
  q = wred_sum(q);
  if ((threadIdx.x & 63) == 0) red[threadIdx.x >> 6] = q;
  __syncthreads();
  const float var = (red[0] + red[1] + red[2] + red[3]) * (1.f / Hc);
  const float inv = rsqrtf(var + EPSc);
  #pragma unroll
  for (int i = 0; i < 4; ++i) {
    const int col = threadIdx.x + (i << 8);
    x[base + col] = (v[i] - mean) * inv * g[col] + b[col];
  }
}

// gumbel one-hot -> code rows (z_soft == y_hard numerically)
__global__ void gumbel_k(const float* __restrict__ z, const float* __restrict__ gn,
                         const float* __restrict__ cb, float* __restrict__ zcodes) {
  const int b = blockIdx.x, t = threadIdx.x;
  if (t >= NEc) return;
  const float* zp = z + b * (NEc * NCc) + t * NCc;
  const float* gp = gn + (b * NEc + t) * NCc;
  int best = 0; float bv = -3.4e38f;
  for (int c2 = 0; c2 < NCc; ++c2) {
    const float val = (zp[c2] + gp[c2]) * (1.f / TAUc);
    if (val > bv) { bv = val; best = c2; }   // strict > == jnp.argmax first-max
  }
  for (int d2 = 0; d2 < CDc; ++d2)
    zcodes[(b * NEc + t) * CDc + d2] = cb[best * CDc + d2];
}

__global__ void build_hwk_k(const float* __restrict__ hctx, const float* __restrict__ zcodes,
                            float* __restrict__ hwk) {
  const int r = blockIdx.x;
  const int b = r >> 2;
  for (int i = threadIdx.x; i < Hc + CDc; i += 256)
    hwk[r * (Hc + CDc) + i] = (i < Hc) ? hctx[b * Hc + i] : zcodes[r * CDc + (i - Hc)];
}

// tv normalize + info gain + argmax select -> chosen
__global__ void select_k(const float* __restrict__ tv, const float* __restrict__ outc,
                         float* __restrict__ chosen) {
  const int b = blockIdx.x, t = threadIdx.x;   // 128 threads
  __shared__ float red[2];
  __shared__ float ig[NEc];
  __shared__ int bestIdx;
  const float x = tv[b * ODc + t];
  float ss = wred_sum(x * x);
  if ((t & 63) == 0) red[t >> 6] = ss;
  __syncthreads();
  float nrm = fmaxf(sqrtf(red[0] + red[1]), 1e-12f);
  const float tvn = x / nrm;
  __syncthreads();
  for (int ne = 0; ne < NEc; ++ne) {
    const float o = outc[(b * NEc + ne) * ODc + t];
    float a = wred_sum(o * o);
    float d2 = wred_sum(o * tvn);
    if ((t & 63) == 0) red[t >> 6] = a;
    __syncthreads();
    const float no = sqrtf(red[0] + red[1]);
    __syncthreads();
    if ((t & 63) == 0) red[t >> 6] = d2;
    __syncthreads();
    const float dd = red[0] + red[1];
    if (t == 0) ig[ne] = dd / fmaxf(no, 1e-12f) * (1.f / TEMPc);
    __syncthreads();
  }
  if (t == 0) {
    int bi = 0; float bvv = ig[0];
    for (int ne = 1; ne < NEc; ++ne) if (ig[ne] > bvv) { bvv = ig[ne]; bi = ne; }
    bestIdx = bi;
  }
  __syncthreads();
  chosen[b * ODc + t] = outc[(b * NEc + bestIdx) * ODc + t];
}

// fused = gamma*hidden + beta  (bf16 out)
__global__ void fuse_k(const float* __restrict__ hs, const float* __restrict__ gb,
                       u16* __restrict__ fused) {
  const long i = (((long)blockIdx.x << 8) + threadIdx.x) << 2;
  const int h = (int)(i & (Hc - 1));
  const int b = (int)(i >> 21);   // / (S*H) = 2^21
  const float4 xv = *(const float4*)(hs + i);
  const float* gp = gb + b * 2048;
  s16x4 pk = { (short)f2bf(fmaf(gp[h + 0], xv.x, gp[Hc + h + 0])),
               (short)f2bf(fmaf(gp[h + 1], xv.y, gp[Hc + h + 1])),
               (short)f2bf(fmaf(gp[h + 2], xv.z, gp[Hc + h + 2])),
               (short)f2bf(fmaf(gp[h + 3], xv.w, gp[Hc + h + 3])) };
  *(s16x4*)(fused + i) = pk;
}

// row softmax over 2048 bf16 scores (in-place), with attention mask.
// Vectorized: thread t owns contiguous cols [t*8, t*8+8) -> 16B load/store.
__global__ void softmax_k(u16* __restrict__ sc, const int* __restrict__ mask) {
  const long base = (long)blockIdx.x * Sc;
  const int b = blockIdx.x / Sc;
  const int t = threadIdx.x;
  __shared__ float red[4];
  s16x8 v8 = *(s16x8*)&sc[base + t * 8];
  const int4 m0 = *(const int4*)&mask[b * Sc + t * 8];
  const int4 m1 = *(const int4*)&mask[b * Sc + t * 8 + 4];
  float x[8];
  x[0] = (m0.x == 0) ? -3.0e38f : bf2f((u16)v8[0]);
  x[1] = (m0.y == 0) ? -3.0e38f : bf2f((u16)v8[1]);
  x[2] = (m0.z == 0) ? -3.0e38f : bf2f((u16)v8[2]);
  x[3] = (m0.w == 0) ? -3.0e38f : bf2f((u16)v8[3]);
  x[4] = (m1.x == 0) ? -3.0e38f : bf2f((u16)v8[4]);
  x[5] = (m1.y == 0) ? -3.0e38f : bf2f((u16)v8[5]);
  x[6] = (m1.z == 0) ? -3.0e38f : bf2f((u16)v8[6]);
  x[7] = (m1.w == 0) ? -3.0e38f : bf2f((u16)v8[7]);
  float mx = -3.0e38f;
  #pragma unroll
  for (int i = 0; i < 8; ++i) mx = fmaxf(mx, x[i]);
  mx = wred_max(mx);
  if ((t & 63) == 0) red[t >> 6] = mx;
  __syncthreads();
  mx = fmaxf(fmaxf(red[0], red[1]), fmaxf(red[2], red[3]));
  float sum = 0.f;
  #pragma unroll
  for (int i = 0; i < 8; ++i) { x[i] = __expf(x[i] - mx); sum += x[i]; }
  __syncthreads();
  sum = wred_sum(sum);
  if ((t & 63) == 0) red[t >> 6] = sum;
  __syncthreads();
  const float inv = 1.f / (red[0] + red[1] + red[2] + red[3]);
  s16x8 o8;
  #pragma unroll
  for (int i = 0; i < 8; ++i) o8[i] = (short)f2bf(x[i] * inv);
  *(s16x8*)&sc[base + t * 8] = o8;
}

// out = LN(ff + fused) * g + b   (fp32 out)
__global__ void final_ln_k(const u16* __restrict__ ff, const u16* __restrict__ fused,
                           const float* __restrict__ g, const float* __restrict__ b,
                           float* __restrict__ out) {
  const long base = (long)blockIdx.x * Hc;
  __shared__ float red[4];
  float v[4]; float s = 0.f;
  #pragma unroll
  for (int i = 0; i < 4; ++i) {
    const int col = threadIdx.x + (i << 8);
    v[i] = bf2f(ff[base + col]) + bf2f(fused[base + col]);
    s += v[i];
  }
  s = wred_sum(s);
  if ((threadIdx.x & 63) == 0) red[threadIdx.x >> 6] = s;
  __syncthreads();
  const float mean = (red[0] + red[1] + red[2] + red[3]) * (1.f / Hc);
  float q = 0.f;
  #pragma unroll
  for (int i = 0; i < 4; ++i) { const float d2 = v[i] - mean; q += d2 * d2; }
  __syncthreads();
  q = wred_sum(q);
  if ((threadIdx.x & 63) == 0) red[threadIdx.x >> 6] = q;
  __syncthreads();
  const float var = (red[0] + red[1] + red[2] + red[3]) * (1.f / Hc);
  const float inv = rsqrtf(var + EPSc);
  #pragma unroll
  for (int i = 0; i < 4; ++i) {
    const int col = threadIdx.x + (i << 8);
    out[base + col] = (v[i] - mean) * inv * g[col] + b[col];
  }
}

// ---------------------------------------------------------------------------
extern "C" void kernel_launch(void* const* d_in, const int* in_sizes, int n_in,
                              void* d_out, int out_size, void* d_ws, size_t ws_size,
                              hipStream_t stream) {
  const float* hs       = (const float*)d_in[0];
  const int*   amask    = (const int*)d_in[1];
  const float* gn       = (const float*)d_in[2];
  const float* cp_w     = (const float*)d_in[3];
  const float* cp_b     = (const float*)d_in[4];
  const float* cp_ln_g  = (const float*)d_in[5];
  const float* cp_ln_b  = (const float*)d_in[6];
  const float* eph_w1   = (const float*)d_in[7];
  const float* eph_b1   = (const float*)d_in[8];
  const float* eph_w2   = (const float*)d_in[9];
  const float* eph_b2   = (const float*)d_in[10];
  const float* codebook = (const float*)d_in[11];
  const float* wk_w1    = (const float*)d_in[12];
  const float* wk_b1    = (const float*)d_in[13];
  const float* wk_w2    = (const float*)d_in[14];
  const float* wk_b2    = (const float*)d_in[15];
  const float* tp_w     = (const float*)d_in[16];
  const float* film_w   = (const float*)d_in[17];
  const float* film_b   = (const float*)d_in[18];
  const float* q_w      = (const float*)d_in[19];
  const float* q_bias   = (const float*)d_in[20];
  const float* k_w      = (const float*)d_in[21];
  const float* k_bias   = (const float*)d_in[22];
  const float* v_w      = (const float*)d_in[23];
  const float* v_bias   = (const float*)d_in[24];
  const float* o_w      = (const float*)d_in[25];
  const float* o_bias   = (const float*)d_in[26];
  const float* int_w    = (const float*)d_in[27];
  const float* int_b    = (const float*)d_in[28];
  const float* out_w    = (const float*)d_in[29];
  const float* out_b    = (const float*)d_in[30];
  const float* ln_g     = (const float*)d_in[31];
  const float* ln_b     = (const float*)d_in[32];
  float* outp = (float*)d_out;

  char* w = (char*)d_ws;
  auto alloc = [&](size_t bytes) -> char* {
    char* p = w; w += (bytes + 255) & ~(size_t)255; return p;
  };
  float* part    = (float*)alloc((size_t)Bc * 16 * Hc * 4);
  float* pooled  = (float*)alloc((size_t)Bc * Hc * 4);
  float* hctx    = (float*)alloc((size_t)Bc * Hc * 4);
  float* t1      = (float*)alloc((size_t)Bc * Hc * 4);
  float* zlog    = (float*)alloc((size_t)Bc * 64 * 4);
  float* zcodes  = (float*)alloc((size_t)Bc * NEc * CDc * 4);
  float* hwk     = (float*)alloc((size_t)16 * (Hc + CDc) * 4);
  float* wkt1    = (float*)alloc((size_t)16 * 2048 * 4);
  float* outcome = (float*)alloc((size_t)16 * ODc * 4);
  float* tvb     = (float*)alloc((size_t)Bc * ODc * 4);
  float* chosen  = (float*)alloc((size_t)Bc * ODc * 4);
  float* gb      = (float*)alloc((size_t)Bc * 2048 * 4);
  float* lin_part= (float*)alloc((size_t)1024 * 1024);   // 1 MB split-K partials
  float* qk_bias = (float*)alloc((size_t)2048 * 4);
  u16* qT    = (u16*)alloc((size_t)Hc * Hc * 2);         // qT,kT contiguous -> merged Bt
  u16* kT    = (u16*)alloc((size_t)Hc * Hc * 2);
  u16* vTw   = (u16*)alloc((size_t)Hc * Hc * 2);
  u16* oT    = (u16*)alloc((size_t)Hc * Hc * 2);
  u16* intT  = (u16*)alloc((size_t)Hc * 4096 * 2);
  u16* outT  = (u16*)alloc((size_t)Hc * 4096 * 2);
  u16* fused = (u16*)alloc((size_t)8192 * Hc * 2);
  u16* qkact = (u16*)alloc((size_t)8192 * 2048 * 2);     // q||k, ld 2048 (32 MB)
  u16* scores= (u16*)alloc((size_t)Bc * Sc * Sc * 2);    // 32 MB, right after qkact
  u16* vTact = (u16*)alloc((size_t)8192 * Hc * 2);
  u16* attn  = (u16*)alloc((size_t)8192 * Hc * 2);
  u16* h1    = (u16*)alloc((size_t)8192 * Hc * 2);
  u16* mid = qkact;  // FFN1 out [8192][4096] = qkact(32MB)+scores(32MB), both dead
  u16* ffo = attn;   // attn dead after o-proj

  if ((size_t)(w - (char*)d_ws) > ws_size) return;  // visible failure if ws too small

  const dim3 tb32(32, 8);
  transpose_w4_k<<<dim3(32, 32, 4), tb32, 0, stream>>>(q_w, k_w, v_w, o_w, qT, kT, vTw, oT);
  transpose_w_k<<<dim3(4096 / 32, Hc / 32), tb32, 0, stream>>>(int_w, intT, Hc, 4096);
  transpose_w_k<<<dim3(Hc / 32, 4096 / 32), tb32, 0, stream>>>(out_w, outT, 4096, Hc);
  concat_bias_k<<<8, 256, 0, stream>>>(q_bias, k_bias, qk_bias);

  pool_partial_k<<<dim3(Hc / 256, 16, Bc), 256, 0, stream>>>(hs, amask, part);
  pool_final_k<<<Bc, 256, 0, stream>>>(part, amask, pooled);

  // h_ctx = LN(gelu(pooled @ cp_w + cp_b))
  mrow_part_k<4><<<dim3(32, 8), 256, 0, stream>>>(pooled, cp_w, lin_part, Hc, Hc);
  mrow_reduce_k<true><<<16, 256, 0, stream>>>(lin_part, cp_b, hctx, Hc, 4, 8);
  ln_rows_k<<<Bc, 256, 0, stream>>>(hctx, cp_ln_g, cp_ln_b);
  // t1 = gelu(hctx @ eph_w1 + b1)
  mrow_part_k<4><<<dim3(32, 8), 256, 0, stream>>>(hctx, eph_w1, lin_part, Hc, Hc);
  mrow_reduce_k<true><<<16, 256, 0, stream>>>(lin_part, eph_b1, t1, Hc, 4, 8);
  // zlog = t1 @ eph_w2 + b2
  mrow_part_k<4><<<dim3(2, 16), 256, 0, stream>>>(t1, eph_w2, lin_part, Hc, 64);
  mrow_reduce_k<false><<<1, 256, 0, stream>>>(lin_part, eph_b2, zlog, 64, 4, 16);
  gumbel_k<<<Bc, 64, 0, stream>>>(zlog, gn, codebook, zcodes);
  build_hwk_k<<<Bc * NEc, 256, 0, stream>>>(hctx, zcodes, hwk);
  // wkt1 = gelu(hwk @ wk_w1 + b1)   (16 x 1088 x 2048)
  mrow_part_k<16><<<dim3(64, 8), 256, 0, stream>>>(hwk, wk_w1, lin_part, Hc + CDc, 2048);
  mrow_reduce_k<true><<<128, 256, 0, stream>>>(lin_part, wk_b1, wkt1, 2048, 16, 8);
  // outcome = wkt1 @ wk_w2 + b2    (16 x 2048 x 128)
  mrow_part_k<16><<<dim3(4, 32), 256, 0, stream>>>(wkt1, wk_w2, lin_part, 2048, ODc);
  mrow_reduce_k<false><<<8, 256, 0, stream>>>(lin_part, wk_b2, outcome, ODc, 16, 32);
  // tv = hctx @ tp_w
  mrow_part_k<4><<<dim3(4, 8), 256, 0, stream>>>(hctx, tp_w, lin_part, Hc, ODc);
  mrow_reduce_k<false><<<2, 256, 0, stream>>>(lin_part, nullptr, tvb, ODc, 4, 8);
  select_k<<<Bc, 128, 0, stream>>>(tvb, outcome, chosen);
  // gb = gelu(chosen @ film_w + film_b)  (4 x 128 x 2048)
  mrow_part_k<4><<<dim3(64, 2), 256, 0, stream>>>(chosen, film_w, lin_part, ODc, 2048);
  mrow_reduce_k<true><<<32, 256, 0, stream>>>(lin_part, film_b, gb, 2048, 4, 2);
  fuse_k<<<8192, 256, 0, stream>>>(hs, gb, fused);

  // merged q||k projection: [8192][1024] @ [2048][1024]^T -> [8192][2048]
  gemm_bt<1><<<dim3(1024), 256, 0, stream>>>(fused, 0, Hc, qT, 0, Hc, qkact, 0, 2048,
                                             qk_bias, nullptr, 0, 1.f, 8192, 2048, Hc);
  // v written transposed ([H][B*S]) for the PV GEMM
  gemm_bt<9><<<dim3(512), 256, 0, stream>>>(fused, 0, Hc, vTw, 0, Hc, vTact, 0, 8192,
                                            v_bias, nullptr, 0, 1.f, 8192, Hc, Hc);
  // scores = q @ k^T / 32  (per batch; q = qkact cols 0-1023, k = cols 1024-2047)
  gemm_bt<0><<<dim3(256, 1, Bc), 256, 0, stream>>>(qkact, (long)Sc * 2048, 2048,
                                                   qkact + 1024, (long)Sc * 2048, 2048,
                                                   scores, (long)Sc * Sc, Sc,
                                                   nullptr, nullptr, 0, 0.03125f, Sc, Sc, Hc);
  softmax_k<<<Bc * Sc, 256, 0, stream>>>(scores, amask);
  // attn_out = P @ V   (Bt = vTact slice per batch)
  gemm_bt<0><<<dim3(128, 1, Bc), 256, 0, stream>>>(scores, (long)Sc * Sc, Sc,
                                                   vTact, (long)Sc, 8192,
                                                   attn, (long)Sc * Hc, Hc,
                                                   nullptr, nullptr, 0, 1.f, Sc, Hc, Sc);
  // o-proj + bias + residual(fused) -> h1
  gemm_bt<5><<<dim3(512), 256, 0, stream>>>(attn, 0, Hc, oT, 0, Hc, h1, 0, Hc,
                                            o_bias, fused, 0, 1.f, 8192, Hc, Hc);
  // FFN
  gemm_bt<3><<<dim3(2048), 256, 0, stream>>>(h1, 0, Hc, intT, 0, Hc, mid, 0, 4096,
                                             int_b, nullptr, 0, 1.f, 8192, 4096, Hc);
  gemm_bt<1><<<dim3(512), 256, 0, stream>>>(mid, 0, 4096, outT, 0, 4096, ffo, 0, Hc,
                                            out_b, nullptr, 0, 1.f, 8192, Hc, 4096);
  final_ln_k<<<Bc * Sc, 256, 0, stream>>>(ffo, fused, ln_g, ln_b, outp);
}